// Round 19
// baseline (348.762 us; speedup 1.0000x reference)
//
#include <hip/hip_runtime.h>

#define BB   16384
#define NAg  5
#define DD   128
#define HH   128
#define G4   512   // 4*H
#define KC   256   // LS1 + H
#define AA   64
#define CATW 768   // 6*H

typedef __attribute__((ext_vector_type(8))) short bf16x8;
typedef __attribute__((ext_vector_type(4))) float f32x4;

#define DEV static __device__ __forceinline__

DEV unsigned short bf16r(float x){
  unsigned u = __float_as_uint(x);
  unsigned r = (u + 0x7fffu + ((u >> 16) & 1u)) >> 16;
  return (unsigned short)r;
}
// fast sigmoid/tanh: v_rcp_f32 (1 ULP) instead of IEEE division
DEV float sigf(float x){ return __builtin_amdgcn_rcpf(1.0f + __expf(-x)); }
DEV float tanhf_(float x){ return __builtin_fmaf(2.0f, __builtin_amdgcn_rcpf(1.0f + __expf(-2.0f * x)), -1.0f); }

DEV bf16x8 ld8(const unsigned short* p){ return *(const bf16x8*)p; }

DEV bf16x8 cvt8(const float* __restrict__ p){
  const float4* q = (const float4*)p;
  float4 v0 = q[0], v1 = q[1];
  bf16x8 r;
  r[0]=(short)bf16r(v0.x); r[1]=(short)bf16r(v0.y); r[2]=(short)bf16r(v0.z); r[3]=(short)bf16r(v0.w);
  r[4]=(short)bf16r(v1.x); r[5]=(short)bf16r(v1.y); r[6]=(short)bf16r(v1.z); r[7]=(short)bf16r(v1.w);
  return r;
}

// ---------------- prep: pack weights bf16; Wm/Wc -> per-wave reg-frag layout -
// [n][w][q][kt][lane][8]: lane holds W[g=q*128+w*16+(lane&15)][k=kt*32+(lane>>4)*8+e]
__global__ void k_prep(const float* __restrict__ d1w, const float* __restrict__ d2w,
                       const float* __restrict__ mWih, const float* __restrict__ mWhh,
                       const float* __restrict__ mbih, const float* __restrict__ mbhh,
                       const float* __restrict__ cWih, const float* __restrict__ cWhh,
                       const float* __restrict__ cbih, const float* __restrict__ cbhh,
                       unsigned short* d1w_bf, unsigned short* d2w_bf,
                       unsigned short* Wm, unsigned short* Wc, float* bm, float* bc)
{
  const long long TOT = 16384 + 49152 + 655360 + 655360 + 2560 + 2560;
  for (long long i = (long long)blockIdx.x * 256 + threadIdx.x; i < TOT;
       i += (long long)gridDim.x * 256) {
    long long x = i;
    if (x < 16384) { d1w_bf[x] = bf16r(d1w[x]); continue; }
    x -= 16384;
    if (x < 49152) { d2w_bf[x] = bf16r(d2w[x]); continue; }
    x -= 49152;
    if (x < 655360) {
      int e    = (int)(x & 7);
      int lane = (int)((x >> 3) & 63);
      int kt   = (int)((x >> 9) & 7);
      int q    = (int)((x >> 12) & 3);
      int w    = (int)((x >> 14) & 7);
      int n    = (int)(x >> 17);
      int g = q * 128 + w * 16 + (lane & 15);
      int k = kt * 32 + (lane >> 4) * 8 + e;
      Wm[x] = bf16r(k < 128 ? mWih[((size_t)n * 512 + g) * 128 + k]
                            : mWhh[((size_t)n * 512 + g) * 128 + (k - 128)]);
      continue;
    }
    x -= 655360;
    if (x < 655360) {
      int e    = (int)(x & 7);
      int lane = (int)((x >> 3) & 63);
      int kt   = (int)((x >> 9) & 7);
      int q    = (int)((x >> 12) & 3);
      int w    = (int)((x >> 14) & 7);
      int l0   = (int)(x >> 17);
      int g = q * 128 + w * 16 + (lane & 15);
      int k = kt * 32 + (lane >> 4) * 8 + e;
      Wc[x] = bf16r(k < 128 ? cWih[((size_t)l0 * 512 + g) * 128 + k]
                            : cWhh[((size_t)l0 * 512 + g) * 128 + (k - 128)]);
      continue;
    }
    x -= 655360;
    if (x < 2560) { bm[x] = mbih[x] + mbhh[x]; continue; }
    x -= 2560;
    bc[x] = cbih[x] + cbhh[x];
  }
}

// ---------------- fused obs-GEMM + mem-LSTM (W streamed, bias-init acc) ------
__global__ __launch_bounds__(512) void k_memobs(const float* __restrict__ input,
                                                const unsigned short* __restrict__ d1w,
                                                const float* __restrict__ d1b,
                                                const float* __restrict__ h0,
                                                const float* __restrict__ c0,
                                                const unsigned short* __restrict__ Wmp,
                                                const float* __restrict__ bm,
                                                float* __restrict__ out_h,
                                                float* __restrict__ out_c,
                                                unsigned short* __restrict__ cat,
                                                unsigned short* __restrict__ obs_bf)
{
  __shared__ __align__(16) unsigned short os[64][128];  // 16 KB obs bf16 (swizzled)
  __shared__ __align__(16) float hs[64][128];           // 32 KB f32 staging

  const int n = blockIdx.x >> 8;
  const int b0 = (blockIdx.x & 255) << 6;
  const int tid = threadIdx.x;
  const int w = tid >> 6, lane = tid & 63;
  const int c0l = lane & 15, hi = lane >> 4;
  const int u = w * 16 + c0l;

  const unsigned short* Wg = Wmp + (size_t)n * 131072 + (size_t)w * 16384 + lane * 8;

  // ---- obs phase: wave w computes d1-cols [w*16, w*16+16) for 64 rows ------
  const float biasD = d1b[u];
  f32x4 oacc[4];
  #pragma unroll
  for (int mt = 0; mt < 4; mt++) oacc[mt] = (f32x4){biasD, biasD, biasD, biasD};

  #pragma unroll
  for (int kt = 0; kt < 4; ++kt) {
    const int k = kt * 32 + hi * 8;
    bf16x8 bfrD = ld8(d1w + (size_t)u * DD + k);       // d1w row u
    #pragma unroll
    for (int mt = 0; mt < 4; mt++) {
      const int br = b0 + mt * 16 + c0l;               // batch row
      bf16x8 a = cvt8(input + ((size_t)br * NAg + n) * DD + k);
      oacc[mt] = __builtin_amdgcn_mfma_f32_16x16x32_bf16(a, bfrD, oacc[mt], 0, 0, 0);
    }
  }
  #pragma unroll
  for (int mt = 0; mt < 4; mt++) {
    #pragma unroll
    for (int j = 0; j < 4; j++) {
      const int r = mt * 16 + hi * 4 + j;
      os[r][u ^ ((r & 7) << 3)] = bf16r(oacc[mt][j]);
    }
  }
  __syncthreads();
  // copy os -> obs_bf (linear store; global stays swizzled for k_comf's DMA)
  #pragma unroll
  for (int cc = 0; cc < 2; ++cc) {
    const int idx = cc * 512 + tid;
    const int r = idx >> 4;
    const int c8 = (idx & 15) << 3;
    bf16x8 v = *(const bf16x8*)&os[r][c8];
    *(bf16x8*)(obs_bf + ((size_t)n * BB + b0 + r) * DD + c8) = v;
  }

  // ---- mem-LSTM phase (obs from LDS, W streamed from L2, bias in acc) ------
  const float bI = bm[n * G4 + u];
  const float bF = bm[n * G4 + 128 + u];
  const float bG = bm[n * G4 + 256 + u];
  const float bO = bm[n * G4 + 384 + u];

  float cnr[2][2][4];

  #pragma unroll
  for (int hh = 0; hh < 2; hh++) {
    f32x4 acc[2][4];
    #pragma unroll
    for (int m2 = 0; m2 < 2; m2++) {
      acc[m2][0] = (f32x4){bI, bI, bI, bI};
      acc[m2][1] = (f32x4){bF, bF, bF, bF};
      acc[m2][2] = (f32x4){bG, bG, bG, bG};
      acc[m2][3] = (f32x4){bO, bO, bO, bO};
    }

    #pragma unroll
    for (int kt = 0; kt < 8; ++kt) {
      bf16x8 bfr[4];
      #pragma unroll
      for (int q = 0; q < 4; q++) bfr[q] = ld8(Wg + (q * 8 + kt) * 512);
      bf16x8 a[2];
      #pragma unroll
      for (int m2 = 0; m2 < 2; m2++) {
        const int r = (hh * 2 + m2) * 16 + c0l;
        if (kt < 4) a[m2] = ld8(&os[r][(kt * 32 + hi * 8) ^ ((r & 7) << 3)]);
        else        a[m2] = cvt8(h0 + ((size_t)n * BB + b0 + r) * HH + (kt - 4) * 32 + hi * 8);
      }
      #pragma unroll
      for (int m2 = 0; m2 < 2; m2++)
        #pragma unroll
        for (int q = 0; q < 4; q++)
          acc[m2][q] = __builtin_amdgcn_mfma_f32_16x16x32_bf16(a[m2], bfr[q], acc[m2][q], 0, 0, 0);
    }

    #pragma unroll
    for (int m2 = 0; m2 < 2; m2++) {
      #pragma unroll
      for (int j = 0; j < 4; j++) {
        const int r = hh * 32 + m2 * 16 + hi * 4 + j;
        const float iv = acc[m2][0][j];
        const float fv = acc[m2][1][j];
        const float gv = acc[m2][2][j];
        const float ov = acc[m2][3][j];
        const float cold = c0[((size_t)n * BB + b0 + r) * HH + u];
        const float cn = sigf(fv) * cold + sigf(iv) * tanhf_(gv);
        const float hn = sigf(ov) * tanhf_(cn);
        cnr[hh][m2][j] = cn;
        hs[r][u ^ ((r & 7) << 3)] = hn;
      }
    }
  }
  __syncthreads();
  // out_h copy (float4, full lines)
  #pragma unroll
  for (int cc = 0; cc < 4; ++cc) {
    const int idx = cc * 512 + tid;
    const int r = idx >> 5;
    const int c4 = (idx & 31) << 2;
    float4 v = *(const float4*)&hs[r][c4 ^ ((r & 7) << 3)];
    *(float4*)(out_h + ((size_t)n * BB + b0 + r) * HH + c4) = v;
  }
  // cat copy (bf16x8, full lines)
  #pragma unroll
  for (int cc = 0; cc < 2; ++cc) {
    const int idx = cc * 512 + tid;
    const int r = idx >> 4;
    const int c8 = (idx & 15) << 3;
    const float* p = &hs[r][c8 ^ ((r & 7) << 3)];
    float4 v0 = *(const float4*)p, v1 = *(const float4*)(p + 4);
    bf16x8 bv;
    bv[0]=(short)bf16r(v0.x); bv[1]=(short)bf16r(v0.y); bv[2]=(short)bf16r(v0.z); bv[3]=(short)bf16r(v0.w);
    bv[4]=(short)bf16r(v1.x); bv[5]=(short)bf16r(v1.y); bv[6]=(short)bf16r(v1.z); bv[7]=(short)bf16r(v1.w);
    *(bf16x8*)(cat + ((size_t)n * BB + b0 + r) * CATW + 640 + c8) = bv;
  }
  __syncthreads();
  // stage c and copy
  #pragma unroll
  for (int hh = 0; hh < 2; hh++)
    #pragma unroll
    for (int m2 = 0; m2 < 2; m2++)
      #pragma unroll
      for (int j = 0; j < 4; j++) {
        const int r = hh * 32 + m2 * 16 + hi * 4 + j;
        hs[r][u ^ ((r & 7) << 3)] = cnr[hh][m2][j];
      }
  __syncthreads();
  #pragma unroll
  for (int cc = 0; cc < 4; ++cc) {
    const int idx = cc * 512 + tid;
    const int r = idx >> 5;
    const int c4 = (idx & 31) << 2;
    float4 v = *(const float4*)&hs[r][c4 ^ ((r & 7) << 3)];
    *(float4*)(out_c + ((size_t)n * BB + b0 + r) * HH + c4) = v;
  }
}

// ---------------- fused com scan: reg-W + obs LDS prefetch + bias-init -------
__global__ __launch_bounds__(512) void k_comf(const unsigned short* __restrict__ obs_bf,
                                              const unsigned short* __restrict__ Wpk,
                                              const float* __restrict__ bc,
                                              unsigned short* __restrict__ cat)
{
  __shared__ __align__(16) unsigned short hl[2][64][128];   // 32 KB
  __shared__ __align__(16) unsigned short ol[2][64][128];   // 32 KB obs dbuf

  const int bid = blockIdx.x;
  const int swz = (bid & 7) * 160 + (bid >> 3);   // 1280 = 8*160, bijective
  const int l0 = swz >> 8;
  const int b0 = (swz & 255) << 6;
  const int tid = threadIdx.x;
  const int w = tid >> 6, lane = tid & 63;
  const int c0l = lane & 15, hi = lane >> 4;
  const int u = w * 16 + c0l;

  const unsigned short* Wg = Wpk + (size_t)l0 * 131072 + (size_t)w * 16384 + lane * 8;
  bf16x8 wfr[4][8];
  #pragma unroll
  for (int q = 0; q < 4; q++)
    #pragma unroll
    for (int kt = 0; kt < 8; kt++)
      wfr[q][kt] = ld8(Wg + (q * 8 + kt) * 512);

  const float bI = bc[l0 * G4 + u];
  const float bF = bc[l0 * G4 + 128 + u];
  const float bG = bc[l0 * G4 + 256 + u];
  const float bO = bc[l0 * G4 + 384 + u];

  // zero h(-1) buffer (hl[1], read by t=0)
  for (int i = tid; i < 8192; i += 512) ((unsigned short*)hl)[8192 + i] = 0;

  // prologue DMA: obs tile of step 0 -> ol[0]; per-wave LDS base + w*512
  {
    const int it0 = (0 == 4) ? l0 : (0 + (0 >= l0 ? 1 : 0));
    const unsigned short* src = obs_bf + ((size_t)it0 * BB + b0) * DD;
    __builtin_amdgcn_global_load_lds((const unsigned int*)(src + tid * 8),
                                     (unsigned int*)((unsigned short*)ol + w * 512), 16, 0, 0);
    __builtin_amdgcn_global_load_lds((const unsigned int*)(src + 4096 + tid * 8),
                                     (unsigned int*)((unsigned short*)ol + 4096 + w * 512), 16, 0, 0);
  }
  __syncthreads();

  float creg[2][2][4];
  #pragma unroll
  for (int hh = 0; hh < 2; hh++)
    #pragma unroll
    for (int m2 = 0; m2 < 2; m2++)
      #pragma unroll
      for (int j = 0; j < 4; j++) creg[hh][m2][j] = 0.0f;

  for (int t = 0; t < 5; ++t) {
    const int it = (t == 4) ? l0 : (t + (t >= l0 ? 1 : 0));
    const int rbuf = (t + 1) & 1, wbuf = t & 1;
    const int ob_c = t & 1, ob_n = (t + 1) & 1;

    if (t < 4) {
      const int tn = t + 1;
      const int itn = (tn == 4) ? l0 : (tn + (tn >= l0 ? 1 : 0));
      const unsigned short* src = obs_bf + ((size_t)itn * BB + b0) * DD;
      unsigned short* dst = (unsigned short*)ol + ob_n * 8192 + w * 512;
      __builtin_amdgcn_global_load_lds((const unsigned int*)(src + tid * 8),
                                       (unsigned int*)dst, 16, 0, 0);
      __builtin_amdgcn_global_load_lds((const unsigned int*)(src + 4096 + tid * 8),
                                       (unsigned int*)(dst + 4096), 16, 0, 0);
    }

    #pragma unroll
    for (int hh = 0; hh < 2; hh++) {
      f32x4 acc[2][4];
      #pragma unroll
      for (int m2 = 0; m2 < 2; m2++) {
        acc[m2][0] = (f32x4){bI, bI, bI, bI};
        acc[m2][1] = (f32x4){bF, bF, bF, bF};
        acc[m2][2] = (f32x4){bG, bG, bG, bG};
        acc[m2][3] = (f32x4){bO, bO, bO, bO};
      }

      #pragma unroll
      for (int kt = 0; kt < 4; ++kt) {
        bf16x8 a[2];
        #pragma unroll
        for (int m2 = 0; m2 < 2; m2++) {
          const int r = (hh * 2 + m2) * 16 + c0l;
          a[m2] = ld8(&ol[ob_c][r][(kt * 32 + hi * 8) ^ ((r & 7) << 3)]);
        }
        #pragma unroll
        for (int m2 = 0; m2 < 2; m2++)
          #pragma unroll
          for (int q = 0; q < 4; q++)
            acc[m2][q] = __builtin_amdgcn_mfma_f32_16x16x32_bf16(a[m2], wfr[q][kt], acc[m2][q], 0, 0, 0);
      }

      if (hh == 0) __syncthreads();   // hl[rbuf] from step t-1 certified

      #pragma unroll
      for (int kt = 4; kt < 8; ++kt) {
        bf16x8 a[2];
        #pragma unroll
        for (int m2 = 0; m2 < 2; m2++) {
          const int r = (hh * 2 + m2) * 16 + c0l;
          a[m2] = ld8(&hl[rbuf][r][((kt - 4) * 32 + hi * 8) ^ ((r & 7) << 3)]);
        }
        #pragma unroll
        for (int m2 = 0; m2 < 2; m2++)
          #pragma unroll
          for (int q = 0; q < 4; q++)
            acc[m2][q] = __builtin_amdgcn_mfma_f32_16x16x32_bf16(a[m2], wfr[q][kt], acc[m2][q], 0, 0, 0);
      }

      #pragma unroll
      for (int m2 = 0; m2 < 2; m2++) {
        #pragma unroll
        for (int j = 0; j < 4; j++) {
          const int r = hh * 32 + m2 * 16 + hi * 4 + j;
          const float iv = acc[m2][0][j];
          const float fv = acc[m2][1][j];
          const float gv = acc[m2][2][j];
          const float ov = acc[m2][3][j];
          const float cn = sigf(fv) * creg[hh][m2][j] + sigf(iv) * tanhf_(gv);
          const float hn = sigf(ov) * tanhf_(cn);
          creg[hh][m2][j] = cn;
          hl[wbuf][r][u ^ ((r & 7) << 3)] = bf16r(hn);
        }
      }
    }
    __syncthreads();

    unsigned short* catb = cat + ((size_t)it * BB + b0) * CATW + l0 * 128;
    #pragma unroll
    for (int cc = 0; cc < 2; ++cc) {
      const int idx = cc * 512 + tid;
      const int r = idx >> 4;
      const int c8 = (idx & 15) << 3;
      bf16x8 v = *(const bf16x8*)&hl[wbuf][r][c8 ^ ((r & 7) << 3)];
      *(bf16x8*)(catb + (size_t)r * CATW + c8) = v;
    }
  }
}

// ---------------- outs = cat @ d2_w^T + d2_b, 128 rows/block -----------------
__global__ __launch_bounds__(256) void k_d2(const unsigned short* __restrict__ cat,
                                            const unsigned short* __restrict__ d2w,
                                            const float* __restrict__ d2b,
                                            float* __restrict__ out)
{
  const int m0 = blockIdx.x * 128;
  const int w = threadIdx.x >> 6, l = threadIdx.x & 63;
  const int c0l = l & 15, hi = l >> 4;

  const unsigned short* arow0 = cat + (size_t)(m0 + w * 16 + c0l) * CATW;
  const unsigned short* arow1 = arow0 + (size_t)64 * CATW;
  f32x4 acc[2][4];
  #pragma unroll
  for (int mt = 0; mt < 2; mt++)
    #pragma unroll
    for (int nt = 0; nt < 4; nt++) acc[mt][nt] = (f32x4){0, 0, 0, 0};

  #pragma unroll 4
  for (int kt = 0; kt < 24; ++kt) {
    const int k = kt * 32 + hi * 8;
    bf16x8 a0 = ld8(arow0 + k);
    bf16x8 a1 = ld8(arow1 + k);
    #pragma unroll
    for (int nt = 0; nt < 4; nt++) {
      bf16x8 bfr = ld8(d2w + (size_t)(nt * 16 + c0l) * CATW + k);
      acc[0][nt] = __builtin_amdgcn_mfma_f32_16x16x32_bf16(a0, bfr, acc[0][nt], 0, 0, 0);
      acc[1][nt] = __builtin_amdgcn_mfma_f32_16x16x32_bf16(a1, bfr, acc[1][nt], 0, 0, 0);
    }
  }
  #pragma unroll
  for (int mt = 0; mt < 2; mt++) {
    #pragma unroll
    for (int nt = 0; nt < 4; nt++) {
      const int col = nt * 16 + c0l;
      const float bias = d2b[col];
      #pragma unroll
      for (int j = 0; j < 4; j++) {
        const int r = m0 + mt * 64 + w * 16 + hi * 4 + j;
        out[(size_t)r * AA + col] = acc[mt][nt][j] + bias;
      }
    }
  }
}

extern "C" void kernel_launch(void* const* d_in, const int* in_sizes, int n_in,
                              void* d_out, int out_size, void* d_ws, size_t ws_size,
                              hipStream_t stream)
{
  const float* input = (const float*)d_in[0];
  const float* h0    = (const float*)d_in[1];
  const float* c0    = (const float*)d_in[2];
  const float* d1w   = (const float*)d_in[3];
  const float* d1b   = (const float*)d_in[4];
  const float* d2w   = (const float*)d_in[5];
  const float* d2b   = (const float*)d_in[6];
  const float* mWih  = (const float*)d_in[7];
  const float* mWhh  = (const float*)d_in[8];
  const float* mbih  = (const float*)d_in[9];
  const float* mbhh  = (const float*)d_in[10];
  const float* cWih  = (const float*)d_in[11];
  const float* cWhh  = (const float*)d_in[12];
  const float* cbih  = (const float*)d_in[13];
  const float* cbhh  = (const float*)d_in[14];
  float* out = (float*)d_out;

  char* ws = (char*)d_ws;
  size_t off = 0;
  auto alloc = [&](size_t bytes) { void* p = ws + off; off += (bytes + 255) & ~255ull; return p; };
  unsigned short* d1w_bf = (unsigned short*)alloc(16384 * 2);
  unsigned short* d2w_bf = (unsigned short*)alloc(49152 * 2);
  unsigned short* Wm     = (unsigned short*)alloc(655360 * 2);
  unsigned short* Wcb    = (unsigned short*)alloc(655360 * 2);
  float* bm              = (float*)alloc(2560 * 4);
  float* bc              = (float*)alloc(2560 * 4);
  unsigned short* obs_bf = (unsigned short*)alloc((size_t)NAg * BB * DD * 2);
  unsigned short* cat    = (unsigned short*)alloc((size_t)NAg * BB * CATW * 2);

  float* out_h = out + (size_t)NAg * BB * AA;
  float* out_c = out_h + (size_t)NAg * BB * HH;

  k_prep<<<2048, 256, 0, stream>>>(d1w, d2w, mWih, mWhh, mbih, mbhh,
                                   cWih, cWhh, cbih, cbhh,
                                   d1w_bf, d2w_bf, Wm, Wcb, bm, bc);
  k_memobs<<<(NAg * BB) / 64, 512, 0, stream>>>(input, d1w_bf, d1b, h0, c0, Wm, bm,
                                                out_h, out_c, cat, obs_bf);
  k_comf<<<(NAg * BB) / 64, 512, 0, stream>>>(obs_bf, Wcb, bc, cat);
  k_d2<<<(NAg * BB) / 128, 256, 0, stream>>>(cat, d2w_bf, d2b, out);
}

// Round 20
// 316.405 us; speedup vs baseline: 1.1023x; 1.1023x over previous
//
#include <hip/hip_runtime.h>

#define BB   16384
#define NAg  5
#define DD   128
#define HH   128
#define G4   512   // 4*H
#define KC   256   // LS1 + H
#define AA   64
#define CATW 768   // 6*H

typedef __attribute__((ext_vector_type(8))) short bf16x8;
typedef __attribute__((ext_vector_type(4))) float f32x4;

#define DEV static __device__ __forceinline__

DEV unsigned short bf16r(float x){
  unsigned u = __float_as_uint(x);
  unsigned r = (u + 0x7fffu + ((u >> 16) & 1u)) >> 16;
  return (unsigned short)r;
}
// fast sigmoid/tanh: v_rcp_f32 (1 ULP) instead of IEEE division
DEV float sigf(float x){ return __builtin_amdgcn_rcpf(1.0f + __expf(-x)); }
DEV float tanhf_(float x){ return __builtin_fmaf(2.0f, __builtin_amdgcn_rcpf(1.0f + __expf(-2.0f * x)), -1.0f); }

DEV bf16x8 ld8(const unsigned short* p){ return *(const bf16x8*)p; }

DEV bf16x8 cvt8(const float* __restrict__ p){
  const float4* q = (const float4*)p;
  float4 v0 = q[0], v1 = q[1];
  bf16x8 r;
  r[0]=(short)bf16r(v0.x); r[1]=(short)bf16r(v0.y); r[2]=(short)bf16r(v0.z); r[3]=(short)bf16r(v0.w);
  r[4]=(short)bf16r(v1.x); r[5]=(short)bf16r(v1.y); r[6]=(short)bf16r(v1.z); r[7]=(short)bf16r(v1.w);
  return r;
}

// ---------------- prep: pack weights bf16; Wm/Wc -> per-wave reg-frag layout;
// h0 -> bf16 swizzled tile layout (matches obs_bf/ol: [row][col^((row&7)<<3)]).
__global__ void k_prep(const float* __restrict__ d1w, const float* __restrict__ d2w,
                       const float* __restrict__ mWih, const float* __restrict__ mWhh,
                       const float* __restrict__ mbih, const float* __restrict__ mbhh,
                       const float* __restrict__ cWih, const float* __restrict__ cWhh,
                       const float* __restrict__ cbih, const float* __restrict__ cbhh,
                       const float* __restrict__ h0,
                       unsigned short* d1w_bf, unsigned short* d2w_bf,
                       unsigned short* Wm, unsigned short* Wc, float* bm, float* bc,
                       unsigned short* h0bf)
{
  const long long TOT = 16384 + 49152 + 655360 + 655360 + 2560 + 2560 + 10485760ll;
  for (long long i = (long long)blockIdx.x * 256 + threadIdx.x; i < TOT;
       i += (long long)gridDim.x * 256) {
    long long x = i;
    if (x < 16384) { d1w_bf[x] = bf16r(d1w[x]); continue; }
    x -= 16384;
    if (x < 49152) { d2w_bf[x] = bf16r(d2w[x]); continue; }
    x -= 49152;
    if (x < 655360) {
      int e    = (int)(x & 7);
      int lane = (int)((x >> 3) & 63);
      int kt   = (int)((x >> 9) & 7);
      int q    = (int)((x >> 12) & 3);
      int w    = (int)((x >> 14) & 7);
      int n    = (int)(x >> 17);
      int g = q * 128 + w * 16 + (lane & 15);
      int k = kt * 32 + (lane >> 4) * 8 + e;
      Wm[x] = bf16r(k < 128 ? mWih[((size_t)n * 512 + g) * 128 + k]
                            : mWhh[((size_t)n * 512 + g) * 128 + (k - 128)]);
      continue;
    }
    x -= 655360;
    if (x < 655360) {
      int e    = (int)(x & 7);
      int lane = (int)((x >> 3) & 63);
      int kt   = (int)((x >> 9) & 7);
      int q    = (int)((x >> 12) & 3);
      int w    = (int)((x >> 14) & 7);
      int l0   = (int)(x >> 17);
      int g = q * 128 + w * 16 + (lane & 15);
      int k = kt * 32 + (lane >> 4) * 8 + e;
      Wc[x] = bf16r(k < 128 ? cWih[((size_t)l0 * 512 + g) * 128 + k]
                            : cWhh[((size_t)l0 * 512 + g) * 128 + (k - 128)]);
      continue;
    }
    x -= 655360;
    if (x < 2560) { bm[x] = mbih[x] + mbhh[x]; continue; }
    x -= 2560;
    if (x < 2560) { bc[x] = cbih[x] + cbhh[x]; continue; }
    x -= 2560;
    // h0 -> bf16 swizzled: element x over (n,b,d); row-in-tile = b&63
    {
      int d = (int)(x & 127);
      int b = (int)((x >> 7) & 16383);
      h0bf[(x - d) + (d ^ ((b & 7) << 3))] = bf16r(h0[x]);
    }
  }
}

// ---------------- fused obs-GEMM + mem-LSTM (W resident, h0 via LDS DMA) -----
__global__ __launch_bounds__(512) void k_memobs(const float* __restrict__ input,
                                                const unsigned short* __restrict__ d1w,
                                                const float* __restrict__ d1b,
                                                const unsigned short* __restrict__ h0bf,
                                                const float* __restrict__ c0,
                                                const unsigned short* __restrict__ Wmp,
                                                const float* __restrict__ bm,
                                                float* __restrict__ out_h,
                                                float* __restrict__ out_c,
                                                unsigned short* __restrict__ cat,
                                                unsigned short* __restrict__ obs_bf)
{
  __shared__ __align__(16) unsigned short os[64][128];  // 16 KB obs (swizzled)
  __shared__ __align__(16) unsigned short hb[64][128];  // 16 KB h0 tile (swizzled)
  __shared__ __align__(16) float hs[64][128];           // 32 KB f32 staging

  const int n = blockIdx.x >> 8;
  const int b0 = (blockIdx.x & 255) << 6;
  const int tid = threadIdx.x;
  const int w = tid >> 6, lane = tid & 63;
  const int c0l = lane & 15, hi = lane >> 4;
  const int u = w * 16 + c0l;

  // DMA h0 tile (pre-swizzled in global) -> hb; drains at first barrier.
  {
    const unsigned short* src = h0bf + ((size_t)n * BB + b0) * DD;
    __builtin_amdgcn_global_load_lds((const unsigned int*)(src + tid * 8),
                                     (unsigned int*)((unsigned short*)hb + w * 512), 16, 0, 0);
    __builtin_amdgcn_global_load_lds((const unsigned int*)(src + 4096 + tid * 8),
                                     (unsigned int*)((unsigned short*)hb + 4096 + w * 512), 16, 0, 0);
  }

  // mem W fragments (resident; each frag one contiguous 1KB line)
  const unsigned short* Wg = Wmp + (size_t)n * 131072 + (size_t)w * 16384 + lane * 8;
  bf16x8 wfr[4][8];
  #pragma unroll
  for (int q = 0; q < 4; q++)
    #pragma unroll
    for (int kt = 0; kt < 8; kt++)
      wfr[q][kt] = ld8(Wg + (q * 8 + kt) * 512);

  // ---- obs phase: wave w computes d1-cols [w*16, w*16+16) for 64 rows ------
  const float biasD = d1b[u];
  f32x4 oacc[4];
  #pragma unroll
  for (int mt = 0; mt < 4; mt++) oacc[mt] = (f32x4){biasD, biasD, biasD, biasD};

  #pragma unroll
  for (int kt = 0; kt < 4; ++kt) {
    const int k = kt * 32 + hi * 8;
    bf16x8 bfrD = ld8(d1w + (size_t)u * DD + k);       // d1w row u
    #pragma unroll
    for (int mt = 0; mt < 4; mt++) {
      const int br = b0 + mt * 16 + c0l;               // batch row
      bf16x8 a = cvt8(input + ((size_t)br * NAg + n) * DD + k);
      oacc[mt] = __builtin_amdgcn_mfma_f32_16x16x32_bf16(a, bfrD, oacc[mt], 0, 0, 0);
    }
  }
  #pragma unroll
  for (int mt = 0; mt < 4; mt++) {
    #pragma unroll
    for (int j = 0; j < 4; j++) {
      const int r = mt * 16 + hi * 4 + j;
      os[r][u ^ ((r & 7) << 3)] = bf16r(oacc[mt][j]);
    }
  }
  __syncthreads();   // certifies os AND drains h0 DMA
  // copy os -> obs_bf (linear store; global stays swizzled for k_comf's DMA)
  #pragma unroll
  for (int cc = 0; cc < 2; ++cc) {
    const int idx = cc * 512 + tid;
    const int r = idx >> 4;
    const int c8 = (idx & 15) << 3;
    bf16x8 v = *(const bf16x8*)&os[r][c8];
    *(bf16x8*)(obs_bf + ((size_t)n * BB + b0 + r) * DD + c8) = v;
  }

  // ---- mem-LSTM phase (obs + h from LDS, W in registers, bias in acc) ------
  const float bI = bm[n * G4 + u];
  const float bF = bm[n * G4 + 128 + u];
  const float bG = bm[n * G4 + 256 + u];
  const float bO = bm[n * G4 + 384 + u];

  float cnr[2][2][4];

  #pragma unroll
  for (int hh = 0; hh < 2; hh++) {
    f32x4 acc[2][4];
    #pragma unroll
    for (int m2 = 0; m2 < 2; m2++) {
      acc[m2][0] = (f32x4){bI, bI, bI, bI};
      acc[m2][1] = (f32x4){bF, bF, bF, bF};
      acc[m2][2] = (f32x4){bG, bG, bG, bG};
      acc[m2][3] = (f32x4){bO, bO, bO, bO};
    }

    #pragma unroll
    for (int kt = 0; kt < 8; ++kt) {
      bf16x8 a[2];
      #pragma unroll
      for (int m2 = 0; m2 < 2; m2++) {
        const int r = (hh * 2 + m2) * 16 + c0l;
        if (kt < 4) a[m2] = ld8(&os[r][(kt * 32 + hi * 8) ^ ((r & 7) << 3)]);
        else        a[m2] = ld8(&hb[r][((kt - 4) * 32 + hi * 8) ^ ((r & 7) << 3)]);
      }
      #pragma unroll
      for (int m2 = 0; m2 < 2; m2++)
        #pragma unroll
        for (int q = 0; q < 4; q++)
          acc[m2][q] = __builtin_amdgcn_mfma_f32_16x16x32_bf16(a[m2], wfr[q][kt], acc[m2][q], 0, 0, 0);
    }

    #pragma unroll
    for (int m2 = 0; m2 < 2; m2++) {
      #pragma unroll
      for (int j = 0; j < 4; j++) {
        const int r = hh * 32 + m2 * 16 + hi * 4 + j;
        const float iv = acc[m2][0][j];
        const float fv = acc[m2][1][j];
        const float gv = acc[m2][2][j];
        const float ov = acc[m2][3][j];
        const float cold = c0[((size_t)n * BB + b0 + r) * HH + u];
        const float cn = sigf(fv) * cold + sigf(iv) * tanhf_(gv);
        const float hn = sigf(ov) * tanhf_(cn);
        cnr[hh][m2][j] = cn;
        hs[r][u ^ ((r & 7) << 3)] = hn;
      }
    }
  }
  __syncthreads();
  // out_h copy (float4, full lines)
  #pragma unroll
  for (int cc = 0; cc < 4; ++cc) {
    const int idx = cc * 512 + tid;
    const int r = idx >> 5;
    const int c4 = (idx & 31) << 2;
    float4 v = *(const float4*)&hs[r][c4 ^ ((r & 7) << 3)];
    *(float4*)(out_h + ((size_t)n * BB + b0 + r) * HH + c4) = v;
  }
  // cat copy (bf16x8, full lines)
  #pragma unroll
  for (int cc = 0; cc < 2; ++cc) {
    const int idx = cc * 512 + tid;
    const int r = idx >> 4;
    const int c8 = (idx & 15) << 3;
    const float* p = &hs[r][c8 ^ ((r & 7) << 3)];
    float4 v0 = *(const float4*)p, v1 = *(const float4*)(p + 4);
    bf16x8 bv;
    bv[0]=(short)bf16r(v0.x); bv[1]=(short)bf16r(v0.y); bv[2]=(short)bf16r(v0.z); bv[3]=(short)bf16r(v0.w);
    bv[4]=(short)bf16r(v1.x); bv[5]=(short)bf16r(v1.y); bv[6]=(short)bf16r(v1.z); bv[7]=(short)bf16r(v1.w);
    *(bf16x8*)(cat + ((size_t)n * BB + b0 + r) * CATW + 640 + c8) = bv;
  }
  __syncthreads();
  // stage c and copy
  #pragma unroll
  for (int hh = 0; hh < 2; hh++)
    #pragma unroll
    for (int m2 = 0; m2 < 2; m2++)
      #pragma unroll
      for (int j = 0; j < 4; j++) {
        const int r = hh * 32 + m2 * 16 + hi * 4 + j;
        hs[r][u ^ ((r & 7) << 3)] = cnr[hh][m2][j];
      }
  __syncthreads();
  #pragma unroll
  for (int cc = 0; cc < 4; ++cc) {
    const int idx = cc * 512 + tid;
    const int r = idx >> 5;
    const int c4 = (idx & 31) << 2;
    float4 v = *(const float4*)&hs[r][c4 ^ ((r & 7) << 3)];
    *(float4*)(out_c + ((size_t)n * BB + b0 + r) * HH + c4) = v;
  }
}

// ---------------- fused com scan: reg-W + obs LDS prefetch + bias-init -------
__global__ __launch_bounds__(512) void k_comf(const unsigned short* __restrict__ obs_bf,
                                              const unsigned short* __restrict__ Wpk,
                                              const float* __restrict__ bc,
                                              unsigned short* __restrict__ cat)
{
  __shared__ __align__(16) unsigned short hl[2][64][128];   // 32 KB
  __shared__ __align__(16) unsigned short ol[2][64][128];   // 32 KB obs dbuf

  const int bid = blockIdx.x;
  const int swz = (bid & 7) * 160 + (bid >> 3);   // 1280 = 8*160, bijective
  const int l0 = swz >> 8;
  const int b0 = (swz & 255) << 6;
  const int tid = threadIdx.x;
  const int w = tid >> 6, lane = tid & 63;
  const int c0l = lane & 15, hi = lane >> 4;
  const int u = w * 16 + c0l;

  const unsigned short* Wg = Wpk + (size_t)l0 * 131072 + (size_t)w * 16384 + lane * 8;
  bf16x8 wfr[4][8];
  #pragma unroll
  for (int q = 0; q < 4; q++)
    #pragma unroll
    for (int kt = 0; kt < 8; kt++)
      wfr[q][kt] = ld8(Wg + (q * 8 + kt) * 512);

  const float bI = bc[l0 * G4 + u];
  const float bF = bc[l0 * G4 + 128 + u];
  const float bG = bc[l0 * G4 + 256 + u];
  const float bO = bc[l0 * G4 + 384 + u];

  // zero h(-1) buffer (hl[1], read by t=0)
  for (int i = tid; i < 8192; i += 512) ((unsigned short*)hl)[8192 + i] = 0;

  // prologue DMA: obs tile of step 0 -> ol[0]; per-wave LDS base + w*512
  {
    const int it0 = (0 == 4) ? l0 : (0 + (0 >= l0 ? 1 : 0));
    const unsigned short* src = obs_bf + ((size_t)it0 * BB + b0) * DD;
    __builtin_amdgcn_global_load_lds((const unsigned int*)(src + tid * 8),
                                     (unsigned int*)((unsigned short*)ol + w * 512), 16, 0, 0);
    __builtin_amdgcn_global_load_lds((const unsigned int*)(src + 4096 + tid * 8),
                                     (unsigned int*)((unsigned short*)ol + 4096 + w * 512), 16, 0, 0);
  }
  __syncthreads();

  float creg[2][2][4];
  #pragma unroll
  for (int hh = 0; hh < 2; hh++)
    #pragma unroll
    for (int m2 = 0; m2 < 2; m2++)
      #pragma unroll
      for (int j = 0; j < 4; j++) creg[hh][m2][j] = 0.0f;

  for (int t = 0; t < 5; ++t) {
    const int it = (t == 4) ? l0 : (t + (t >= l0 ? 1 : 0));
    const int rbuf = (t + 1) & 1, wbuf = t & 1;
    const int ob_c = t & 1, ob_n = (t + 1) & 1;

    if (t < 4) {
      const int tn = t + 1;
      const int itn = (tn == 4) ? l0 : (tn + (tn >= l0 ? 1 : 0));
      const unsigned short* src = obs_bf + ((size_t)itn * BB + b0) * DD;
      unsigned short* dst = (unsigned short*)ol + ob_n * 8192 + w * 512;
      __builtin_amdgcn_global_load_lds((const unsigned int*)(src + tid * 8),
                                       (unsigned int*)dst, 16, 0, 0);
      __builtin_amdgcn_global_load_lds((const unsigned int*)(src + 4096 + tid * 8),
                                       (unsigned int*)(dst + 4096), 16, 0, 0);
    }

    #pragma unroll
    for (int hh = 0; hh < 2; hh++) {
      f32x4 acc[2][4];
      #pragma unroll
      for (int m2 = 0; m2 < 2; m2++) {
        acc[m2][0] = (f32x4){bI, bI, bI, bI};
        acc[m2][1] = (f32x4){bF, bF, bF, bF};
        acc[m2][2] = (f32x4){bG, bG, bG, bG};
        acc[m2][3] = (f32x4){bO, bO, bO, bO};
      }

      #pragma unroll
      for (int kt = 0; kt < 4; ++kt) {
        bf16x8 a[2];
        #pragma unroll
        for (int m2 = 0; m2 < 2; m2++) {
          const int r = (hh * 2 + m2) * 16 + c0l;
          a[m2] = ld8(&ol[ob_c][r][(kt * 32 + hi * 8) ^ ((r & 7) << 3)]);
        }
        #pragma unroll
        for (int m2 = 0; m2 < 2; m2++)
          #pragma unroll
          for (int q = 0; q < 4; q++)
            acc[m2][q] = __builtin_amdgcn_mfma_f32_16x16x32_bf16(a[m2], wfr[q][kt], acc[m2][q], 0, 0, 0);
      }

      if (hh == 0) __syncthreads();   // hl[rbuf] from step t-1 certified

      #pragma unroll
      for (int kt = 4; kt < 8; ++kt) {
        bf16x8 a[2];
        #pragma unroll
        for (int m2 = 0; m2 < 2; m2++) {
          const int r = (hh * 2 + m2) * 16 + c0l;
          a[m2] = ld8(&hl[rbuf][r][((kt - 4) * 32 + hi * 8) ^ ((r & 7) << 3)]);
        }
        #pragma unroll
        for (int m2 = 0; m2 < 2; m2++)
          #pragma unroll
          for (int q = 0; q < 4; q++)
            acc[m2][q] = __builtin_amdgcn_mfma_f32_16x16x32_bf16(a[m2], wfr[q][kt], acc[m2][q], 0, 0, 0);
      }

      #pragma unroll
      for (int m2 = 0; m2 < 2; m2++) {
        #pragma unroll
        for (int j = 0; j < 4; j++) {
          const int r = hh * 32 + m2 * 16 + hi * 4 + j;
          const float iv = acc[m2][0][j];
          const float fv = acc[m2][1][j];
          const float gv = acc[m2][2][j];
          const float ov = acc[m2][3][j];
          const float cn = sigf(fv) * creg[hh][m2][j] + sigf(iv) * tanhf_(gv);
          const float hn = sigf(ov) * tanhf_(cn);
          creg[hh][m2][j] = cn;
          hl[wbuf][r][u ^ ((r & 7) << 3)] = bf16r(hn);
        }
      }
    }
    __syncthreads();

    unsigned short* catb = cat + ((size_t)it * BB + b0) * CATW + l0 * 128;
    #pragma unroll
    for (int cc = 0; cc < 2; ++cc) {
      const int idx = cc * 512 + tid;
      const int r = idx >> 4;
      const int c8 = (idx & 15) << 3;
      bf16x8 v = *(const bf16x8*)&hl[wbuf][r][c8 ^ ((r & 7) << 3)];
      *(bf16x8*)(catb + (size_t)r * CATW + c8) = v;
    }
  }
}

// ---------------- outs = cat @ d2_w^T + d2_b, 128 rows/block -----------------
__global__ __launch_bounds__(256) void k_d2(const unsigned short* __restrict__ cat,
                                            const unsigned short* __restrict__ d2w,
                                            const float* __restrict__ d2b,
                                            float* __restrict__ out)
{
  const int m0 = blockIdx.x * 128;
  const int w = threadIdx.x >> 6, l = threadIdx.x & 63;
  const int c0l = l & 15, hi = l >> 4;

  const unsigned short* arow0 = cat + (size_t)(m0 + w * 16 + c0l) * CATW;
  const unsigned short* arow1 = arow0 + (size_t)64 * CATW;
  f32x4 acc[2][4];
  #pragma unroll
  for (int mt = 0; mt < 2; mt++)
    #pragma unroll
    for (int nt = 0; nt < 4; nt++) acc[mt][nt] = (f32x4){0, 0, 0, 0};

  #pragma unroll 4
  for (int kt = 0; kt < 24; ++kt) {
    const int k = kt * 32 + hi * 8;
    bf16x8 a0 = ld8(arow0 + k);
    bf16x8 a1 = ld8(arow1 + k);
    #pragma unroll
    for (int nt = 0; nt < 4; nt++) {
      bf16x8 bfr = ld8(d2w + (size_t)(nt * 16 + c0l) * CATW + k);
      acc[0][nt] = __builtin_amdgcn_mfma_f32_16x16x32_bf16(a0, bfr, acc[0][nt], 0, 0, 0);
      acc[1][nt] = __builtin_amdgcn_mfma_f32_16x16x32_bf16(a1, bfr, acc[1][nt], 0, 0, 0);
    }
  }
  #pragma unroll
  for (int mt = 0; mt < 2; mt++) {
    #pragma unroll
    for (int nt = 0; nt < 4; nt++) {
      const int col = nt * 16 + c0l;
      const float bias = d2b[col];
      #pragma unroll
      for (int j = 0; j < 4; j++) {
        const int r = m0 + mt * 64 + w * 16 + hi * 4 + j;
        out[(size_t)r * AA + col] = acc[mt][nt][j] + bias;
      }
    }
  }
}

extern "C" void kernel_launch(void* const* d_in, const int* in_sizes, int n_in,
                              void* d_out, int out_size, void* d_ws, size_t ws_size,
                              hipStream_t stream)
{
  const float* input = (const float*)d_in[0];
  const float* h0    = (const float*)d_in[1];
  const float* c0    = (const float*)d_in[2];
  const float* d1w   = (const float*)d_in[3];
  const float* d1b   = (const float*)d_in[4];
  const float* d2w   = (const float*)d_in[5];
  const float* d2b   = (const float*)d_in[6];
  const float* mWih  = (const float*)d_in[7];
  const float* mWhh  = (const float*)d_in[8];
  const float* mbih  = (const float*)d_in[9];
  const float* mbhh  = (const float*)d_in[10];
  const float* cWih  = (const float*)d_in[11];
  const float* cWhh  = (const float*)d_in[12];
  const float* cbih  = (const float*)d_in[13];
  const float* cbhh  = (const float*)d_in[14];
  float* out = (float*)d_out;

  char* ws = (char*)d_ws;
  size_t off = 0;
  auto alloc = [&](size_t bytes) { void* p = ws + off; off += (bytes + 255) & ~255ull; return p; };
  unsigned short* d1w_bf = (unsigned short*)alloc(16384 * 2);
  unsigned short* d2w_bf = (unsigned short*)alloc(49152 * 2);
  unsigned short* Wm     = (unsigned short*)alloc(655360 * 2);
  unsigned short* Wcb    = (unsigned short*)alloc(655360 * 2);
  float* bm              = (float*)alloc(2560 * 4);
  float* bc              = (float*)alloc(2560 * 4);
  unsigned short* obs_bf = (unsigned short*)alloc((size_t)NAg * BB * DD * 2);
  unsigned short* cat    = (unsigned short*)alloc((size_t)NAg * BB * CATW * 2);
  unsigned short* h0bf   = (unsigned short*)alloc((size_t)NAg * BB * DD * 2);

  float* out_h = out + (size_t)NAg * BB * AA;
  float* out_c = out_h + (size_t)NAg * BB * HH;

  k_prep<<<2048, 256, 0, stream>>>(d1w, d2w, mWih, mWhh, mbih, mbhh,
                                   cWih, cWhh, cbih, cbhh, h0,
                                   d1w_bf, d2w_bf, Wm, Wcb, bm, bc, h0bf);
  k_memobs<<<(NAg * BB) / 64, 512, 0, stream>>>(input, d1w_bf, d1b, h0bf, c0, Wm, bm,
                                                out_h, out_c, cat, obs_bf);
  k_comf<<<(NAg * BB) / 64, 512, 0, stream>>>(obs_bf, Wcb, bc, cat);
  k_d2<<<(NAg * BB) / 128, 256, 0, stream>>>(cat, d2w_bf, d2b, out);
}

// Round 21
// 313.893 us; speedup vs baseline: 1.1111x; 1.0080x over previous
//
#include <hip/hip_runtime.h>

#define BB   16384
#define NAg  5
#define DD   128
#define HH   128
#define G4   512   // 4*H
#define KC   256   // LS1 + H
#define AA   64
#define CATW 768   // 6*H

typedef __attribute__((ext_vector_type(8))) short bf16x8;
typedef __attribute__((ext_vector_type(4))) float f32x4;

#define DEV static __device__ __forceinline__

DEV unsigned short bf16r(float x){
  unsigned u = __float_as_uint(x);
  unsigned r = (u + 0x7fffu + ((u >> 16) & 1u)) >> 16;
  return (unsigned short)r;
}
DEV float rcpf(float x){ return __builtin_amdgcn_rcpf(x); }

// fused LSTM cell math, 5 exp + 3 rcp per output:
// cn = cold*rcp(1+e^-f) + (1-e^-2g)*rcp((1+e^-i)(1+e^-2g))
// hn = (1-e^-2cn)*rcp((1+e^-o)(1+e^-2cn))
DEV void lstm_cell(float iv, float fv, float gv, float ov, float cold,
                   float& cn, float& hn){
  float ef = __expf(-fv), ei = __expf(-iv), eg = __expf(-2.0f * gv);
  cn = cold * rcpf(1.0f + ef) + (1.0f - eg) * rcpf((1.0f + ei) * (1.0f + eg));
  float eo = __expf(-ov), ec = __expf(-2.0f * cn);
  hn = (1.0f - ec) * rcpf((1.0f + eo) * (1.0f + ec));
}

DEV bf16x8 ld8(const unsigned short* p){ return *(const bf16x8*)p; }

DEV bf16x8 cvt8(const float* __restrict__ p){
  const float4* q = (const float4*)p;
  float4 v0 = q[0], v1 = q[1];
  bf16x8 r;
  r[0]=(short)bf16r(v0.x); r[1]=(short)bf16r(v0.y); r[2]=(short)bf16r(v0.z); r[3]=(short)bf16r(v0.w);
  r[4]=(short)bf16r(v1.x); r[5]=(short)bf16r(v1.y); r[6]=(short)bf16r(v1.z); r[7]=(short)bf16r(v1.w);
  return r;
}

// ---------------- prep: pack weights bf16; Wm/Wc -> per-wave reg-frag layout;
// h0 -> bf16 swizzled tile layout.
__global__ void k_prep(const float* __restrict__ d1w, const float* __restrict__ d2w,
                       const float* __restrict__ mWih, const float* __restrict__ mWhh,
                       const float* __restrict__ mbih, const float* __restrict__ mbhh,
                       const float* __restrict__ cWih, const float* __restrict__ cWhh,
                       const float* __restrict__ cbih, const float* __restrict__ cbhh,
                       const float* __restrict__ h0,
                       unsigned short* d1w_bf, unsigned short* d2w_bf,
                       unsigned short* Wm, unsigned short* Wc, float* bm, float* bc,
                       unsigned short* h0bf)
{
  const long long TOT = 16384 + 49152 + 655360 + 655360 + 2560 + 2560 + 10485760ll;
  for (long long i = (long long)blockIdx.x * 256 + threadIdx.x; i < TOT;
       i += (long long)gridDim.x * 256) {
    long long x = i;
    if (x < 16384) { d1w_bf[x] = bf16r(d1w[x]); continue; }
    x -= 16384;
    if (x < 49152) { d2w_bf[x] = bf16r(d2w[x]); continue; }
    x -= 49152;
    if (x < 655360) {
      int e    = (int)(x & 7);
      int lane = (int)((x >> 3) & 63);
      int kt   = (int)((x >> 9) & 7);
      int q    = (int)((x >> 12) & 3);
      int w    = (int)((x >> 14) & 7);
      int n    = (int)(x >> 17);
      int g = q * 128 + w * 16 + (lane & 15);
      int k = kt * 32 + (lane >> 4) * 8 + e;
      Wm[x] = bf16r(k < 128 ? mWih[((size_t)n * 512 + g) * 128 + k]
                            : mWhh[((size_t)n * 512 + g) * 128 + (k - 128)]);
      continue;
    }
    x -= 655360;
    if (x < 655360) {
      int e    = (int)(x & 7);
      int lane = (int)((x >> 3) & 63);
      int kt   = (int)((x >> 9) & 7);
      int q    = (int)((x >> 12) & 3);
      int w    = (int)((x >> 14) & 7);
      int l0   = (int)(x >> 17);
      int g = q * 128 + w * 16 + (lane & 15);
      int k = kt * 32 + (lane >> 4) * 8 + e;
      Wc[x] = bf16r(k < 128 ? cWih[((size_t)l0 * 512 + g) * 128 + k]
                            : cWhh[((size_t)l0 * 512 + g) * 128 + (k - 128)]);
      continue;
    }
    x -= 655360;
    if (x < 2560) { bm[x] = mbih[x] + mbhh[x]; continue; }
    x -= 2560;
    if (x < 2560) { bc[x] = cbih[x] + cbhh[x]; continue; }
    x -= 2560;
    {
      int d = (int)(x & 127);
      int b = (int)((x >> 7) & 16383);
      h0bf[(x - d) + (d ^ ((b & 7) << 3))] = bf16r(h0[x]);
    }
  }
}

// ---------------- fused obs-GEMM + mem-LSTM (W resident, h0 via LDS DMA) -----
__global__ __launch_bounds__(512) void k_memobs(const float* __restrict__ input,
                                                const unsigned short* __restrict__ d1w,
                                                const float* __restrict__ d1b,
                                                const unsigned short* __restrict__ h0bf,
                                                const float* __restrict__ c0,
                                                const unsigned short* __restrict__ Wmp,
                                                const float* __restrict__ bm,
                                                float* __restrict__ out_h,
                                                float* __restrict__ out_c,
                                                unsigned short* __restrict__ cat,
                                                unsigned short* __restrict__ obs_bf)
{
  __shared__ __align__(16) unsigned short os[64][128];  // 16 KB obs (swizzled)
  __shared__ __align__(16) unsigned short hb[64][128];  // 16 KB h0 tile (swizzled)
  __shared__ __align__(16) float hs[64][128];           // 32 KB h f32 staging
  __shared__ __align__(16) float cs[64][128];           // 32 KB c f32 staging

  const int n = blockIdx.x >> 8;
  const int b0 = (blockIdx.x & 255) << 6;
  const int tid = threadIdx.x;
  const int w = tid >> 6, lane = tid & 63;
  const int c0l = lane & 15, hi = lane >> 4;
  const int u = w * 16 + c0l;

  // DMA h0 tile (pre-swizzled in global) -> hb; drains at first barrier.
  {
    const unsigned short* src = h0bf + ((size_t)n * BB + b0) * DD;
    __builtin_amdgcn_global_load_lds((const unsigned int*)(src + tid * 8),
                                     (unsigned int*)((unsigned short*)hb + w * 512), 16, 0, 0);
    __builtin_amdgcn_global_load_lds((const unsigned int*)(src + 4096 + tid * 8),
                                     (unsigned int*)((unsigned short*)hb + 4096 + w * 512), 16, 0, 0);
  }

  // mem W fragments (resident)
  const unsigned short* Wg = Wmp + (size_t)n * 131072 + (size_t)w * 16384 + lane * 8;
  bf16x8 wfr[4][8];
  #pragma unroll
  for (int q = 0; q < 4; q++)
    #pragma unroll
    for (int kt = 0; kt < 8; kt++)
      wfr[q][kt] = ld8(Wg + (q * 8 + kt) * 512);

  // ---- obs phase ----
  const float biasD = d1b[u];
  f32x4 oacc[4];
  #pragma unroll
  for (int mt = 0; mt < 4; mt++) oacc[mt] = (f32x4){biasD, biasD, biasD, biasD};

  #pragma unroll
  for (int kt = 0; kt < 4; ++kt) {
    const int k = kt * 32 + hi * 8;
    bf16x8 bfrD = ld8(d1w + (size_t)u * DD + k);
    #pragma unroll
    for (int mt = 0; mt < 4; mt++) {
      const int br = b0 + mt * 16 + c0l;
      bf16x8 a = cvt8(input + ((size_t)br * NAg + n) * DD + k);
      oacc[mt] = __builtin_amdgcn_mfma_f32_16x16x32_bf16(a, bfrD, oacc[mt], 0, 0, 0);
    }
  }
  #pragma unroll
  for (int mt = 0; mt < 4; mt++) {
    #pragma unroll
    for (int j = 0; j < 4; j++) {
      const int r = mt * 16 + hi * 4 + j;
      os[r][u ^ ((r & 7) << 3)] = bf16r(oacc[mt][j]);
    }
  }
  __syncthreads();   // certifies os AND drains h0 DMA
  // copy os -> obs_bf (linear; global stays swizzled for k_comf's DMA)
  #pragma unroll
  for (int cc = 0; cc < 2; ++cc) {
    const int idx = cc * 512 + tid;
    const int r = idx >> 4;
    const int c8 = (idx & 15) << 3;
    bf16x8 v = *(const bf16x8*)&os[r][c8];
    *(bf16x8*)(obs_bf + ((size_t)n * BB + b0 + r) * DD + c8) = v;
  }

  // ---- mem-LSTM phase ----
  const float bI = bm[n * G4 + u];
  const float bF = bm[n * G4 + 128 + u];
  const float bG = bm[n * G4 + 256 + u];
  const float bO = bm[n * G4 + 384 + u];

  #pragma unroll
  for (int hh = 0; hh < 2; hh++) {
    f32x4 acc[2][4];
    #pragma unroll
    for (int m2 = 0; m2 < 2; m2++) {
      acc[m2][0] = (f32x4){bI, bI, bI, bI};
      acc[m2][1] = (f32x4){bF, bF, bF, bF};
      acc[m2][2] = (f32x4){bG, bG, bG, bG};
      acc[m2][3] = (f32x4){bO, bO, bO, bO};
    }

    #pragma unroll
    for (int kt = 0; kt < 8; ++kt) {
      bf16x8 a[2];
      #pragma unroll
      for (int m2 = 0; m2 < 2; m2++) {
        const int r = (hh * 2 + m2) * 16 + c0l;
        if (kt < 4) a[m2] = ld8(&os[r][(kt * 32 + hi * 8) ^ ((r & 7) << 3)]);
        else        a[m2] = ld8(&hb[r][((kt - 4) * 32 + hi * 8) ^ ((r & 7) << 3)]);
      }
      #pragma unroll
      for (int m2 = 0; m2 < 2; m2++)
        #pragma unroll
        for (int q = 0; q < 4; q++)
          acc[m2][q] = __builtin_amdgcn_mfma_f32_16x16x32_bf16(a[m2], wfr[q][kt], acc[m2][q], 0, 0, 0);
    }

    #pragma unroll
    for (int m2 = 0; m2 < 2; m2++) {
      #pragma unroll
      for (int j = 0; j < 4; j++) {
        const int r = hh * 32 + m2 * 16 + hi * 4 + j;
        const float cold = c0[((size_t)n * BB + b0 + r) * HH + u];
        float cn, hn;
        lstm_cell(acc[m2][0][j], acc[m2][1][j], acc[m2][2][j], acc[m2][3][j], cold, cn, hn);
        const int sc = u ^ ((r & 7) << 3);
        hs[r][sc] = hn;
        cs[r][sc] = cn;
      }
    }
  }
  __syncthreads();
  // out_h copy (float4, full lines)
  #pragma unroll
  for (int cc = 0; cc < 4; ++cc) {
    const int idx = cc * 512 + tid;
    const int r = idx >> 5;
    const int c4 = (idx & 31) << 2;
    float4 v = *(const float4*)&hs[r][c4 ^ ((r & 7) << 3)];
    *(float4*)(out_h + ((size_t)n * BB + b0 + r) * HH + c4) = v;
  }
  // out_c copy
  #pragma unroll
  for (int cc = 0; cc < 4; ++cc) {
    const int idx = cc * 512 + tid;
    const int r = idx >> 5;
    const int c4 = (idx & 31) << 2;
    float4 v = *(const float4*)&cs[r][c4 ^ ((r & 7) << 3)];
    *(float4*)(out_c + ((size_t)n * BB + b0 + r) * HH + c4) = v;
  }
  // cat copy (bf16x8, full lines)
  #pragma unroll
  for (int cc = 0; cc < 2; ++cc) {
    const int idx = cc * 512 + tid;
    const int r = idx >> 4;
    const int c8 = (idx & 15) << 3;
    const float* p = &hs[r][c8 ^ ((r & 7) << 3)];
    float4 v0 = *(const float4*)p, v1 = *(const float4*)(p + 4);
    bf16x8 bv;
    bv[0]=(short)bf16r(v0.x); bv[1]=(short)bf16r(v0.y); bv[2]=(short)bf16r(v0.z); bv[3]=(short)bf16r(v0.w);
    bv[4]=(short)bf16r(v1.x); bv[5]=(short)bf16r(v1.y); bv[6]=(short)bf16r(v1.z); bv[7]=(short)bf16r(v1.w);
    *(bf16x8*)(cat + ((size_t)n * BB + b0 + r) * CATW + 640 + c8) = bv;
  }
}

// ---------------- fused com scan: reg-W + obs LDS prefetch + t0-skip ---------
__global__ __launch_bounds__(512) void k_comf(const unsigned short* __restrict__ obs_bf,
                                              const unsigned short* __restrict__ Wpk,
                                              const float* __restrict__ bc,
                                              unsigned short* __restrict__ cat)
{
  __shared__ __align__(16) unsigned short hl[2][64][128];   // 32 KB
  __shared__ __align__(16) unsigned short ol[2][64][128];   // 32 KB obs dbuf

  const int bid = blockIdx.x;
  const int swz = (bid & 7) * 160 + (bid >> 3);   // 1280 = 8*160, bijective
  const int l0 = swz >> 8;
  const int b0 = (swz & 255) << 6;
  const int tid = threadIdx.x;
  const int w = tid >> 6, lane = tid & 63;
  const int c0l = lane & 15, hi = lane >> 4;
  const int u = w * 16 + c0l;

  const unsigned short* Wg = Wpk + (size_t)l0 * 131072 + (size_t)w * 16384 + lane * 8;
  bf16x8 wfr[4][8];
  #pragma unroll
  for (int q = 0; q < 4; q++)
    #pragma unroll
    for (int kt = 0; kt < 8; kt++)
      wfr[q][kt] = ld8(Wg + (q * 8 + kt) * 512);

  const float bI = bc[l0 * G4 + u];
  const float bF = bc[l0 * G4 + 128 + u];
  const float bG = bc[l0 * G4 + 256 + u];
  const float bO = bc[l0 * G4 + 384 + u];

  // prologue DMA: obs tile of step 0 -> ol[0]; per-wave LDS base + w*512
  {
    const int it0 = (0 >= l0 ? 1 : 0);
    const unsigned short* src = obs_bf + ((size_t)it0 * BB + b0) * DD;
    __builtin_amdgcn_global_load_lds((const unsigned int*)(src + tid * 8),
                                     (unsigned int*)((unsigned short*)ol + w * 512), 16, 0, 0);
    __builtin_amdgcn_global_load_lds((const unsigned int*)(src + 4096 + tid * 8),
                                     (unsigned int*)((unsigned short*)ol + 4096 + w * 512), 16, 0, 0);
  }
  __syncthreads();

  float creg[2][2][4];
  #pragma unroll
  for (int hh = 0; hh < 2; hh++)
    #pragma unroll
    for (int m2 = 0; m2 < 2; m2++)
      #pragma unroll
      for (int j = 0; j < 4; j++) creg[hh][m2][j] = 0.0f;

  for (int t = 0; t < 5; ++t) {
    const int it = (t == 4) ? l0 : (t + (t >= l0 ? 1 : 0));
    const int rbuf = (t + 1) & 1, wbuf = t & 1;
    const int ob_c = t & 1, ob_n = (t + 1) & 1;

    if (t < 4) {
      const int tn = t + 1;
      const int itn = (tn == 4) ? l0 : (tn + (tn >= l0 ? 1 : 0));
      const unsigned short* src = obs_bf + ((size_t)itn * BB + b0) * DD;
      unsigned short* dst = (unsigned short*)ol + ob_n * 8192 + w * 512;
      __builtin_amdgcn_global_load_lds((const unsigned int*)(src + tid * 8),
                                       (unsigned int*)dst, 16, 0, 0);
      __builtin_amdgcn_global_load_lds((const unsigned int*)(src + 4096 + tid * 8),
                                       (unsigned int*)(dst + 4096), 16, 0, 0);
    }

    #pragma unroll
    for (int hh = 0; hh < 2; hh++) {
      f32x4 acc[2][4];
      #pragma unroll
      for (int m2 = 0; m2 < 2; m2++) {
        acc[m2][0] = (f32x4){bI, bI, bI, bI};
        acc[m2][1] = (f32x4){bF, bF, bF, bF};
        acc[m2][2] = (f32x4){bG, bG, bG, bG};
        acc[m2][3] = (f32x4){bO, bO, bO, bO};
      }

      #pragma unroll
      for (int kt = 0; kt < 4; ++kt) {
        bf16x8 a[2];
        #pragma unroll
        for (int m2 = 0; m2 < 2; m2++) {
          const int r = (hh * 2 + m2) * 16 + c0l;
          a[m2] = ld8(&ol[ob_c][r][(kt * 32 + hi * 8) ^ ((r & 7) << 3)]);
        }
        #pragma unroll
        for (int m2 = 0; m2 < 2; m2++)
          #pragma unroll
          for (int q = 0; q < 4; q++)
            acc[m2][q] = __builtin_amdgcn_mfma_f32_16x16x32_bf16(a[m2], wfr[q][kt], acc[m2][q], 0, 0, 0);
      }

      if (hh == 0) __syncthreads();   // hl[rbuf] from step t-1 certified

      // h-part: skipped at t=0 (h = 0 -> contributes nothing; hl never read)
      if (t > 0) {
        #pragma unroll
        for (int kt = 4; kt < 8; ++kt) {
          bf16x8 a[2];
          #pragma unroll
          for (int m2 = 0; m2 < 2; m2++) {
            const int r = (hh * 2 + m2) * 16 + c0l;
            a[m2] = ld8(&hl[rbuf][r][((kt - 4) * 32 + hi * 8) ^ ((r & 7) << 3)]);
          }
          #pragma unroll
          for (int m2 = 0; m2 < 2; m2++)
            #pragma unroll
            for (int q = 0; q < 4; q++)
              acc[m2][q] = __builtin_amdgcn_mfma_f32_16x16x32_bf16(a[m2], wfr[q][kt], acc[m2][q], 0, 0, 0);
        }
      }

      #pragma unroll
      for (int m2 = 0; m2 < 2; m2++) {
        #pragma unroll
        for (int j = 0; j < 4; j++) {
          const int r = hh * 32 + m2 * 16 + hi * 4 + j;
          float cn, hn;
          lstm_cell(acc[m2][0][j], acc[m2][1][j], acc[m2][2][j], acc[m2][3][j],
                    creg[hh][m2][j], cn, hn);
          creg[hh][m2][j] = cn;
          hl[wbuf][r][u ^ ((r & 7) << 3)] = bf16r(hn);
        }
      }
    }
    __syncthreads();

    unsigned short* catb = cat + ((size_t)it * BB + b0) * CATW + l0 * 128;
    #pragma unroll
    for (int cc = 0; cc < 2; ++cc) {
      const int idx = cc * 512 + tid;
      const int r = idx >> 4;
      const int c8 = (idx & 15) << 3;
      bf16x8 v = *(const bf16x8*)&hl[wbuf][r][c8 ^ ((r & 7) << 3)];
      *(bf16x8*)(catb + (size_t)r * CATW + c8) = v;
    }
  }
}

// ---------------- outs = cat @ d2_w^T + d2_b, 128 rows/block -----------------
__global__ __launch_bounds__(256) void k_d2(const unsigned short* __restrict__ cat,
                                            const unsigned short* __restrict__ d2w,
                                            const float* __restrict__ d2b,
                                            float* __restrict__ out)
{
  const int m0 = blockIdx.x * 128;
  const int w = threadIdx.x >> 6, l = threadIdx.x & 63;
  const int c0l = l & 15, hi = l >> 4;

  const unsigned short* arow0 = cat + (size_t)(m0 + w * 16 + c0l) * CATW;
  const unsigned short* arow1 = arow0 + (size_t)64 * CATW;
  f32x4 acc[2][4];
  #pragma unroll
  for (int mt = 0; mt < 2; mt++)
    #pragma unroll
    for (int nt = 0; nt < 4; nt++) acc[mt][nt] = (f32x4){0, 0, 0, 0};

  #pragma unroll 4
  for (int kt = 0; kt < 24; ++kt) {
    const int k = kt * 32 + hi * 8;
    bf16x8 a0 = ld8(arow0 + k);
    bf16x8 a1 = ld8(arow1 + k);
    #pragma unroll
    for (int nt = 0; nt < 4; nt++) {
      bf16x8 bfr = ld8(d2w + (size_t)(nt * 16 + c0l) * CATW + k);
      acc[0][nt] = __builtin_amdgcn_mfma_f32_16x16x32_bf16(a0, bfr, acc[0][nt], 0, 0, 0);
      acc[1][nt] = __builtin_amdgcn_mfma_f32_16x16x32_bf16(a1, bfr, acc[1][nt], 0, 0, 0);
    }
  }
  #pragma unroll
  for (int mt = 0; mt < 2; mt++) {
    #pragma unroll
    for (int nt = 0; nt < 4; nt++) {
      const int col = nt * 16 + c0l;
      const float bias = d2b[col];
      #pragma unroll
      for (int j = 0; j < 4; j++) {
        const int r = m0 + mt * 64 + w * 16 + hi * 4 + j;
        out[(size_t)r * AA + col] = acc[mt][nt][j] + bias;
      }
    }
  }
}

extern "C" void kernel_launch(void* const* d_in, const int* in_sizes, int n_in,
                              void* d_out, int out_size, void* d_ws, size_t ws_size,
                              hipStream_t stream)
{
  const float* input = (const float*)d_in[0];
  const float* h0    = (const float*)d_in[1];
  const float* c0    = (const float*)d_in[2];
  const float* d1w   = (const float*)d_in[3];
  const float* d1b   = (const float*)d_in[4];
  const float* d2w   = (const float*)d_in[5];
  const float* d2b   = (const float*)d_in[6];
  const float* mWih  = (const float*)d_in[7];
  const float* mWhh  = (const float*)d_in[8];
  const float* mbih  = (const float*)d_in[9];
  const float* mbhh  = (const float*)d_in[10];
  const float* cWih  = (const float*)d_in[11];
  const float* cWhh  = (const float*)d_in[12];
  const float* cbih  = (const float*)d_in[13];
  const float* cbhh  = (const float*)d_in[14];
  float* out = (float*)d_out;

  char* ws = (char*)d_ws;
  size_t off = 0;
  auto alloc = [&](size_t bytes) { void* p = ws + off; off += (bytes + 255) & ~255ull; return p; };
  unsigned short* d1w_bf = (unsigned short*)alloc(16384 * 2);
  unsigned short* d2w_bf = (unsigned short*)alloc(49152 * 2);
  unsigned short* Wm     = (unsigned short*)alloc(655360 * 2);
  unsigned short* Wcb    = (unsigned short*)alloc(655360 * 2);
  float* bm              = (float*)alloc(2560 * 4);
  float* bc              = (float*)alloc(2560 * 4);
  unsigned short* obs_bf = (unsigned short*)alloc((size_t)NAg * BB * DD * 2);
  unsigned short* cat    = (unsigned short*)alloc((size_t)NAg * BB * CATW * 2);
  unsigned short* h0bf   = (unsigned short*)alloc((size_t)NAg * BB * DD * 2);

  float* out_h = out + (size_t)NAg * BB * AA;
  float* out_c = out_h + (size_t)NAg * BB * HH;

  k_prep<<<2048, 256, 0, stream>>>(d1w, d2w, mWih, mWhh, mbih, mbhh,
                                   cWih, cWhh, cbih, cbhh, h0,
                                   d1w_bf, d2w_bf, Wm, Wcb, bm, bc, h0bf);
  k_memobs<<<(NAg * BB) / 64, 512, 0, stream>>>(input, d1w_bf, d1b, h0bf, c0, Wm, bm,
                                                out_h, out_c, cat, obs_bf);
  k_comf<<<(NAg * BB) / 64, 512, 0, stream>>>(obs_bf, Wcb, bc, cat);
  k_d2<<<(NAg * BB) / 128, 256, 0, stream>>>(cat, d2w_bf, d2b, out);
}

// Round 22
// 311.826 us; speedup vs baseline: 1.1185x; 1.0066x over previous
//
#include <hip/hip_runtime.h>

#define BB   16384
#define NAg  5
#define DD   128
#define HH   128
#define G4   512   // 4*H
#define KC   256   // LS1 + H
#define AA   64
#define CATW 768   // 6*H

typedef __attribute__((ext_vector_type(8))) short bf16x8;
typedef __attribute__((ext_vector_type(4))) float f32x4;

#define DEV static __device__ __forceinline__

DEV unsigned short bf16r(float x){
  unsigned u = __float_as_uint(x);
  unsigned r = (u + 0x7fffu + ((u >> 16) & 1u)) >> 16;
  return (unsigned short)r;
}
DEV float rcpf(float x){ return __builtin_amdgcn_rcpf(x); }

// fused LSTM cell math, 5 exp + 3 rcp per output
DEV void lstm_cell(float iv, float fv, float gv, float ov, float cold,
                   float& cn, float& hn){
  float ef = __expf(-fv), ei = __expf(-iv), eg = __expf(-2.0f * gv);
  cn = cold * rcpf(1.0f + ef) + (1.0f - eg) * rcpf((1.0f + ei) * (1.0f + eg));
  float eo = __expf(-ov), ec = __expf(-2.0f * cn);
  hn = (1.0f - ec) * rcpf((1.0f + eo) * (1.0f + ec));
}

DEV bf16x8 ld8(const unsigned short* p){ return *(const bf16x8*)p; }

DEV bf16x8 cvt8(const float* __restrict__ p){
  const float4* q = (const float4*)p;
  float4 v0 = q[0], v1 = q[1];
  bf16x8 r;
  r[0]=(short)bf16r(v0.x); r[1]=(short)bf16r(v0.y); r[2]=(short)bf16r(v0.z); r[3]=(short)bf16r(v0.w);
  r[4]=(short)bf16r(v1.x); r[5]=(short)bf16r(v1.y); r[6]=(short)bf16r(v1.z); r[7]=(short)bf16r(v1.w);
  return r;
}

// ---------------- prep: pack weights bf16; Wm/Wc -> per-wave reg-frag layout;
// h0 -> bf16 swizzled tile layout.
__global__ void k_prep(const float* __restrict__ d1w, const float* __restrict__ d2w,
                       const float* __restrict__ mWih, const float* __restrict__ mWhh,
                       const float* __restrict__ mbih, const float* __restrict__ mbhh,
                       const float* __restrict__ cWih, const float* __restrict__ cWhh,
                       const float* __restrict__ cbih, const float* __restrict__ cbhh,
                       const float* __restrict__ h0,
                       unsigned short* d1w_bf, unsigned short* d2w_bf,
                       unsigned short* Wm, unsigned short* Wc, float* bm, float* bc,
                       unsigned short* h0bf)
{
  const long long TOT = 16384 + 49152 + 655360 + 655360 + 2560 + 2560 + 10485760ll;
  for (long long i = (long long)blockIdx.x * 256 + threadIdx.x; i < TOT;
       i += (long long)gridDim.x * 256) {
    long long x = i;
    if (x < 16384) { d1w_bf[x] = bf16r(d1w[x]); continue; }
    x -= 16384;
    if (x < 49152) { d2w_bf[x] = bf16r(d2w[x]); continue; }
    x -= 49152;
    if (x < 655360) {
      int e    = (int)(x & 7);
      int lane = (int)((x >> 3) & 63);
      int kt   = (int)((x >> 9) & 7);
      int q    = (int)((x >> 12) & 3);
      int w    = (int)((x >> 14) & 7);
      int n    = (int)(x >> 17);
      int g = q * 128 + w * 16 + (lane & 15);
      int k = kt * 32 + (lane >> 4) * 8 + e;
      Wm[x] = bf16r(k < 128 ? mWih[((size_t)n * 512 + g) * 128 + k]
                            : mWhh[((size_t)n * 512 + g) * 128 + (k - 128)]);
      continue;
    }
    x -= 655360;
    if (x < 655360) {
      int e    = (int)(x & 7);
      int lane = (int)((x >> 3) & 63);
      int kt   = (int)((x >> 9) & 7);
      int q    = (int)((x >> 12) & 3);
      int w    = (int)((x >> 14) & 7);
      int l0   = (int)(x >> 17);
      int g = q * 128 + w * 16 + (lane & 15);
      int k = kt * 32 + (lane >> 4) * 8 + e;
      Wc[x] = bf16r(k < 128 ? cWih[((size_t)l0 * 512 + g) * 128 + k]
                            : cWhh[((size_t)l0 * 512 + g) * 128 + (k - 128)]);
      continue;
    }
    x -= 655360;
    if (x < 2560) { bm[x] = mbih[x] + mbhh[x]; continue; }
    x -= 2560;
    if (x < 2560) { bc[x] = cbih[x] + cbhh[x]; continue; }
    x -= 2560;
    {
      int d = (int)(x & 127);
      int b = (int)((x >> 7) & 16383);
      h0bf[(x - d) + (d ^ ((b & 7) << 3))] = bf16r(h0[x]);
    }
  }
}

// ---------------- fused obs-GEMM + mem-LSTM (W resident, h0 via LDS DMA) -----
__global__ __launch_bounds__(512) void k_memobs(const float* __restrict__ input,
                                                const unsigned short* __restrict__ d1w,
                                                const float* __restrict__ d1b,
                                                const unsigned short* __restrict__ h0bf,
                                                const float* __restrict__ c0,
                                                const unsigned short* __restrict__ Wmp,
                                                const float* __restrict__ bm,
                                                float* __restrict__ out_h,
                                                float* __restrict__ out_c,
                                                unsigned short* __restrict__ cat,
                                                unsigned short* __restrict__ obs_bf)
{
  __shared__ __align__(16) unsigned short os[64][128];  // 16 KB obs (swizzled)
  __shared__ __align__(16) unsigned short hb[64][128];  // 16 KB h0 tile (swizzled)
  __shared__ __align__(16) float hs[64][128];           // 32 KB h f32 staging
  __shared__ __align__(16) float cs[64][128];           // 32 KB c f32 staging

  const int n = blockIdx.x >> 8;
  const int b0 = (blockIdx.x & 255) << 6;
  const int tid = threadIdx.x;
  const int w = tid >> 6, lane = tid & 63;
  const int c0l = lane & 15, hi = lane >> 4;
  const int u = w * 16 + c0l;

  // DMA h0 tile (pre-swizzled in global) -> hb; drains at first barrier.
  {
    const unsigned short* src = h0bf + ((size_t)n * BB + b0) * DD;
    __builtin_amdgcn_global_load_lds((const unsigned int*)(src + tid * 8),
                                     (unsigned int*)((unsigned short*)hb + w * 512), 16, 0, 0);
    __builtin_amdgcn_global_load_lds((const unsigned int*)(src + 4096 + tid * 8),
                                     (unsigned int*)((unsigned short*)hb + 4096 + w * 512), 16, 0, 0);
  }

  // mem W fragments (resident)
  const unsigned short* Wg = Wmp + (size_t)n * 131072 + (size_t)w * 16384 + lane * 8;
  bf16x8 wfr[4][8];
  #pragma unroll
  for (int q = 0; q < 4; q++)
    #pragma unroll
    for (int kt = 0; kt < 8; kt++)
      wfr[q][kt] = ld8(Wg + (q * 8 + kt) * 512);

  // ---- obs phase ----
  const float biasD = d1b[u];
  f32x4 oacc[4];
  #pragma unroll
  for (int mt = 0; mt < 4; mt++) oacc[mt] = (f32x4){biasD, biasD, biasD, biasD};

  __builtin_amdgcn_s_setprio(1);
  #pragma unroll
  for (int kt = 0; kt < 4; ++kt) {
    const int k = kt * 32 + hi * 8;
    bf16x8 bfrD = ld8(d1w + (size_t)u * DD + k);
    #pragma unroll
    for (int mt = 0; mt < 4; mt++) {
      const int br = b0 + mt * 16 + c0l;
      bf16x8 a = cvt8(input + ((size_t)br * NAg + n) * DD + k);
      oacc[mt] = __builtin_amdgcn_mfma_f32_16x16x32_bf16(a, bfrD, oacc[mt], 0, 0, 0);
    }
  }
  __builtin_amdgcn_s_setprio(0);
  #pragma unroll
  for (int mt = 0; mt < 4; mt++) {
    #pragma unroll
    for (int j = 0; j < 4; j++) {
      const int r = mt * 16 + hi * 4 + j;
      os[r][u ^ ((r & 7) << 3)] = bf16r(oacc[mt][j]);
    }
  }
  __syncthreads();   // certifies os AND drains h0 DMA
  // copy os -> obs_bf (linear; global stays swizzled for k_comf's DMA)
  #pragma unroll
  for (int cc = 0; cc < 2; ++cc) {
    const int idx = cc * 512 + tid;
    const int r = idx >> 4;
    const int c8 = (idx & 15) << 3;
    bf16x8 v = *(const bf16x8*)&os[r][c8];
    *(bf16x8*)(obs_bf + ((size_t)n * BB + b0 + r) * DD + c8) = v;
  }

  // ---- mem-LSTM phase ----
  const float bI = bm[n * G4 + u];
  const float bF = bm[n * G4 + 128 + u];
  const float bG = bm[n * G4 + 256 + u];
  const float bO = bm[n * G4 + 384 + u];

  #pragma unroll
  for (int hh = 0; hh < 2; hh++) {
    f32x4 acc[2][4];
    #pragma unroll
    for (int m2 = 0; m2 < 2; m2++) {
      acc[m2][0] = (f32x4){bI, bI, bI, bI};
      acc[m2][1] = (f32x4){bF, bF, bF, bF};
      acc[m2][2] = (f32x4){bG, bG, bG, bG};
      acc[m2][3] = (f32x4){bO, bO, bO, bO};
    }

    __builtin_amdgcn_s_setprio(1);
    #pragma unroll
    for (int kt = 0; kt < 8; ++kt) {
      bf16x8 a[2];
      #pragma unroll
      for (int m2 = 0; m2 < 2; m2++) {
        const int r = (hh * 2 + m2) * 16 + c0l;
        if (kt < 4) a[m2] = ld8(&os[r][(kt * 32 + hi * 8) ^ ((r & 7) << 3)]);
        else        a[m2] = ld8(&hb[r][((kt - 4) * 32 + hi * 8) ^ ((r & 7) << 3)]);
      }
      #pragma unroll
      for (int m2 = 0; m2 < 2; m2++)
        #pragma unroll
        for (int q = 0; q < 4; q++)
          acc[m2][q] = __builtin_amdgcn_mfma_f32_16x16x32_bf16(a[m2], wfr[q][kt], acc[m2][q], 0, 0, 0);
    }
    __builtin_amdgcn_s_setprio(0);

    #pragma unroll
    for (int m2 = 0; m2 < 2; m2++) {
      #pragma unroll
      for (int j = 0; j < 4; j++) {
        const int r = hh * 32 + m2 * 16 + hi * 4 + j;
        const float cold = c0[((size_t)n * BB + b0 + r) * HH + u];
        float cn, hn;
        lstm_cell(acc[m2][0][j], acc[m2][1][j], acc[m2][2][j], acc[m2][3][j], cold, cn, hn);
        const int sc = u ^ ((r & 7) << 3);
        hs[r][sc] = hn;
        cs[r][sc] = cn;
      }
    }
  }
  __syncthreads();
  // out_h copy (float4, full lines)
  #pragma unroll
  for (int cc = 0; cc < 4; ++cc) {
    const int idx = cc * 512 + tid;
    const int r = idx >> 5;
    const int c4 = (idx & 31) << 2;
    float4 v = *(const float4*)&hs[r][c4 ^ ((r & 7) << 3)];
    *(float4*)(out_h + ((size_t)n * BB + b0 + r) * HH + c4) = v;
  }
  // out_c copy
  #pragma unroll
  for (int cc = 0; cc < 4; ++cc) {
    const int idx = cc * 512 + tid;
    const int r = idx >> 5;
    const int c4 = (idx & 31) << 2;
    float4 v = *(const float4*)&cs[r][c4 ^ ((r & 7) << 3)];
    *(float4*)(out_c + ((size_t)n * BB + b0 + r) * HH + c4) = v;
  }
  // cat copy (bf16x8, full lines)
  #pragma unroll
  for (int cc = 0; cc < 2; ++cc) {
    const int idx = cc * 512 + tid;
    const int r = idx >> 4;
    const int c8 = (idx & 15) << 3;
    const float* p = &hs[r][c8 ^ ((r & 7) << 3)];
    float4 v0 = *(const float4*)p, v1 = *(const float4*)(p + 4);
    bf16x8 bv;
    bv[0]=(short)bf16r(v0.x); bv[1]=(short)bf16r(v0.y); bv[2]=(short)bf16r(v0.z); bv[3]=(short)bf16r(v0.w);
    bv[4]=(short)bf16r(v1.x); bv[5]=(short)bf16r(v1.y); bv[6]=(short)bf16r(v1.z); bv[7]=(short)bf16r(v1.w);
    *(bf16x8*)(cat + ((size_t)n * BB + b0 + r) * CATW + 640 + c8) = bv;
  }
}

// ---------------- fused com scan: reg-W + obs LDS prefetch + t0-skip ---------
__global__ __launch_bounds__(512) void k_comf(const unsigned short* __restrict__ obs_bf,
                                              const unsigned short* __restrict__ Wpk,
                                              const float* __restrict__ bc,
                                              unsigned short* __restrict__ cat)
{
  __shared__ __align__(16) unsigned short hl[2][64][128];   // 32 KB
  __shared__ __align__(16) unsigned short ol[2][64][128];   // 32 KB obs dbuf

  const int bid = blockIdx.x;
  const int swz = (bid & 7) * 160 + (bid >> 3);   // 1280 = 8*160, bijective
  const int l0 = swz >> 8;
  const int b0 = (swz & 255) << 6;
  const int tid = threadIdx.x;
  const int w = tid >> 6, lane = tid & 63;
  const int c0l = lane & 15, hi = lane >> 4;
  const int u = w * 16 + c0l;

  const unsigned short* Wg = Wpk + (size_t)l0 * 131072 + (size_t)w * 16384 + lane * 8;
  bf16x8 wfr[4][8];
  #pragma unroll
  for (int q = 0; q < 4; q++)
    #pragma unroll
    for (int kt = 0; kt < 8; kt++)
      wfr[q][kt] = ld8(Wg + (q * 8 + kt) * 512);

  const float bI = bc[l0 * G4 + u];
  const float bF = bc[l0 * G4 + 128 + u];
  const float bG = bc[l0 * G4 + 256 + u];
  const float bO = bc[l0 * G4 + 384 + u];

  // prologue DMA: obs tile of step 0 -> ol[0]; per-wave LDS base + w*512
  {
    const int it0 = (0 >= l0 ? 1 : 0);
    const unsigned short* src = obs_bf + ((size_t)it0 * BB + b0) * DD;
    __builtin_amdgcn_global_load_lds((const unsigned int*)(src + tid * 8),
                                     (unsigned int*)((unsigned short*)ol + w * 512), 16, 0, 0);
    __builtin_amdgcn_global_load_lds((const unsigned int*)(src + 4096 + tid * 8),
                                     (unsigned int*)((unsigned short*)ol + 4096 + w * 512), 16, 0, 0);
  }
  __syncthreads();

  float creg[2][2][4];
  #pragma unroll
  for (int hh = 0; hh < 2; hh++)
    #pragma unroll
    for (int m2 = 0; m2 < 2; m2++)
      #pragma unroll
      for (int j = 0; j < 4; j++) creg[hh][m2][j] = 0.0f;

  for (int t = 0; t < 5; ++t) {
    const int it = (t == 4) ? l0 : (t + (t >= l0 ? 1 : 0));
    const int rbuf = (t + 1) & 1, wbuf = t & 1;
    const int ob_c = t & 1, ob_n = (t + 1) & 1;

    if (t < 4) {
      const int tn = t + 1;
      const int itn = (tn == 4) ? l0 : (tn + (tn >= l0 ? 1 : 0));
      const unsigned short* src = obs_bf + ((size_t)itn * BB + b0) * DD;
      unsigned short* dst = (unsigned short*)ol + ob_n * 8192 + w * 512;
      __builtin_amdgcn_global_load_lds((const unsigned int*)(src + tid * 8),
                                       (unsigned int*)dst, 16, 0, 0);
      __builtin_amdgcn_global_load_lds((const unsigned int*)(src + 4096 + tid * 8),
                                       (unsigned int*)(dst + 4096), 16, 0, 0);
    }

    #pragma unroll
    for (int hh = 0; hh < 2; hh++) {
      f32x4 acc[2][4];
      #pragma unroll
      for (int m2 = 0; m2 < 2; m2++) {
        acc[m2][0] = (f32x4){bI, bI, bI, bI};
        acc[m2][1] = (f32x4){bF, bF, bF, bF};
        acc[m2][2] = (f32x4){bG, bG, bG, bG};
        acc[m2][3] = (f32x4){bO, bO, bO, bO};
      }

      __builtin_amdgcn_s_setprio(1);
      #pragma unroll
      for (int kt = 0; kt < 4; ++kt) {
        bf16x8 a[2];
        #pragma unroll
        for (int m2 = 0; m2 < 2; m2++) {
          const int r = (hh * 2 + m2) * 16 + c0l;
          a[m2] = ld8(&ol[ob_c][r][(kt * 32 + hi * 8) ^ ((r & 7) << 3)]);
        }
        #pragma unroll
        for (int m2 = 0; m2 < 2; m2++)
          #pragma unroll
          for (int q = 0; q < 4; q++)
            acc[m2][q] = __builtin_amdgcn_mfma_f32_16x16x32_bf16(a[m2], wfr[q][kt], acc[m2][q], 0, 0, 0);
      }
      __builtin_amdgcn_s_setprio(0);

      if (hh == 0) __syncthreads();   // hl[rbuf] from step t-1 certified

      // h-part: skipped at t=0 (h = 0)
      if (t > 0) {
        __builtin_amdgcn_s_setprio(1);
        #pragma unroll
        for (int kt = 4; kt < 8; ++kt) {
          bf16x8 a[2];
          #pragma unroll
          for (int m2 = 0; m2 < 2; m2++) {
            const int r = (hh * 2 + m2) * 16 + c0l;
            a[m2] = ld8(&hl[rbuf][r][((kt - 4) * 32 + hi * 8) ^ ((r & 7) << 3)]);
          }
          #pragma unroll
          for (int m2 = 0; m2 < 2; m2++)
            #pragma unroll
            for (int q = 0; q < 4; q++)
              acc[m2][q] = __builtin_amdgcn_mfma_f32_16x16x32_bf16(a[m2], wfr[q][kt], acc[m2][q], 0, 0, 0);
        }
        __builtin_amdgcn_s_setprio(0);
      }

      #pragma unroll
      for (int m2 = 0; m2 < 2; m2++) {
        #pragma unroll
        for (int j = 0; j < 4; j++) {
          const int r = hh * 32 + m2 * 16 + hi * 4 + j;
          float cn, hn;
          lstm_cell(acc[m2][0][j], acc[m2][1][j], acc[m2][2][j], acc[m2][3][j],
                    creg[hh][m2][j], cn, hn);
          creg[hh][m2][j] = cn;
          hl[wbuf][r][u ^ ((r & 7) << 3)] = bf16r(hn);
        }
      }
    }
    __syncthreads();

    unsigned short* catb = cat + ((size_t)it * BB + b0) * CATW + l0 * 128;
    #pragma unroll
    for (int cc = 0; cc < 2; ++cc) {
      const int idx = cc * 512 + tid;
      const int r = idx >> 4;
      const int c8 = (idx & 15) << 3;
      bf16x8 v = *(const bf16x8*)&hl[wbuf][r][c8 ^ ((r & 7) << 3)];
      *(bf16x8*)(catb + (size_t)r * CATW + c8) = v;
    }
  }
}

// ---------------- outs = cat @ d2_w^T + d2_b, 256 rows/block (4 m-tiles) -----
__global__ __launch_bounds__(256) void k_d2(const unsigned short* __restrict__ cat,
                                            const unsigned short* __restrict__ d2w,
                                            const float* __restrict__ d2b,
                                            float* __restrict__ out)
{
  const int m0 = blockIdx.x * 256;
  const int w = threadIdx.x >> 6, l = threadIdx.x & 63;
  const int c0l = l & 15, hi = l >> 4;

  const unsigned short* arow[4];
  #pragma unroll
  for (int mt = 0; mt < 4; mt++)
    arow[mt] = cat + (size_t)(m0 + mt * 64 + w * 16 + c0l) * CATW;

  f32x4 acc[4][4];
  #pragma unroll
  for (int mt = 0; mt < 4; mt++)
    #pragma unroll
    for (int nt = 0; nt < 4; nt++) acc[mt][nt] = (f32x4){0, 0, 0, 0};

  #pragma unroll 4
  for (int kt = 0; kt < 24; ++kt) {
    const int k = kt * 32 + hi * 8;
    bf16x8 bfr[4];
    #pragma unroll
    for (int nt = 0; nt < 4; nt++)
      bfr[nt] = ld8(d2w + (size_t)(nt * 16 + c0l) * CATW + k);
    #pragma unroll
    for (int mt = 0; mt < 4; mt++) {
      bf16x8 a = ld8(arow[mt] + k);
      #pragma unroll
      for (int nt = 0; nt < 4; nt++)
        acc[mt][nt] = __builtin_amdgcn_mfma_f32_16x16x32_bf16(a, bfr[nt], acc[mt][nt], 0, 0, 0);
    }
  }
  #pragma unroll
  for (int mt = 0; mt < 4; mt++) {
    #pragma unroll
    for (int nt = 0; nt < 4; nt++) {
      const int col = nt * 16 + c0l;
      const float bias = d2b[col];
      #pragma unroll
      for (int j = 0; j < 4; j++) {
        const int r = m0 + mt * 64 + w * 16 + hi * 4 + j;
        out[(size_t)r * AA + col] = acc[mt][nt][j] + bias;
      }
    }
  }
}

extern "C" void kernel_launch(void* const* d_in, const int* in_sizes, int n_in,
                              void* d_out, int out_size, void* d_ws, size_t ws_size,
                              hipStream_t stream)
{
  const float* input = (const float*)d_in[0];
  const float* h0    = (const float*)d_in[1];
  const float* c0    = (const float*)d_in[2];
  const float* d1w   = (const float*)d_in[3];
  const float* d1b   = (const float*)d_in[4];
  const float* d2w   = (const float*)d_in[5];
  const float* d2b   = (const float*)d_in[6];
  const float* mWih  = (const float*)d_in[7];
  const float* mWhh  = (const float*)d_in[8];
  const float* mbih  = (const float*)d_in[9];
  const float* mbhh  = (const float*)d_in[10];
  const float* cWih  = (const float*)d_in[11];
  const float* cWhh  = (const float*)d_in[12];
  const float* cbih  = (const float*)d_in[13];
  const float* cbhh  = (const float*)d_in[14];
  float* out = (float*)d_out;

  char* ws = (char*)d_ws;
  size_t off = 0;
  auto alloc = [&](size_t bytes) { void* p = ws + off; off += (bytes + 255) & ~255ull; return p; };
  unsigned short* d1w_bf = (unsigned short*)alloc(16384 * 2);
  unsigned short* d2w_bf = (unsigned short*)alloc(49152 * 2);
  unsigned short* Wm     = (unsigned short*)alloc(655360 * 2);
  unsigned short* Wcb    = (unsigned short*)alloc(655360 * 2);
  float* bm              = (float*)alloc(2560 * 4);
  float* bc              = (float*)alloc(2560 * 4);
  unsigned short* obs_bf = (unsigned short*)alloc((size_t)NAg * BB * DD * 2);
  unsigned short* cat    = (unsigned short*)alloc((size_t)NAg * BB * CATW * 2);
  unsigned short* h0bf   = (unsigned short*)alloc((size_t)NAg * BB * DD * 2);

  float* out_h = out + (size_t)NAg * BB * AA;
  float* out_c = out_h + (size_t)NAg * BB * HH;

  k_prep<<<2048, 256, 0, stream>>>(d1w, d2w, mWih, mWhh, mbih, mbhh,
                                   cWih, cWhh, cbih, cbhh, h0,
                                   d1w_bf, d2w_bf, Wm, Wcb, bm, bc, h0bf);
  k_memobs<<<(NAg * BB) / 64, 512, 0, stream>>>(input, d1w_bf, d1b, h0bf, c0, Wm, bm,
                                                out_h, out_c, cat, obs_bf);
  k_comf<<<(NAg * BB) / 64, 512, 0, stream>>>(obs_bf, Wcb, bc, cat);
  k_d2<<<(NAg * BB) / 256, 256, 0, stream>>>(cat, d2w_bf, d2b, out);
}

// Round 23
// 308.780 us; speedup vs baseline: 1.1295x; 1.0099x over previous
//
#include <hip/hip_runtime.h>

#define BB   16384
#define NAg  5
#define DD   128
#define HH   128
#define G4   512   // 4*H
#define KC   256   // LS1 + H
#define AA   64
#define CATW 768   // 6*H

typedef __attribute__((ext_vector_type(8))) short bf16x8;
typedef __attribute__((ext_vector_type(4))) float f32x4;

#define DEV static __device__ __forceinline__

DEV unsigned short bf16r(float x){
  unsigned u = __float_as_uint(x);
  unsigned r = (u + 0x7fffu + ((u >> 16) & 1u)) >> 16;
  return (unsigned short)r;
}
DEV float rcpf(float x){ return __builtin_amdgcn_rcpf(x); }

// fused LSTM cell math, 5 exp + 3 rcp per output
DEV void lstm_cell(float iv, float fv, float gv, float ov, float cold,
                   float& cn, float& hn){
  float ef = __expf(-fv), ei = __expf(-iv), eg = __expf(-2.0f * gv);
  cn = cold * rcpf(1.0f + ef) + (1.0f - eg) * rcpf((1.0f + ei) * (1.0f + eg));
  float eo = __expf(-ov), ec = __expf(-2.0f * cn);
  hn = (1.0f - ec) * rcpf((1.0f + eo) * (1.0f + ec));
}

DEV bf16x8 ld8(const unsigned short* p){ return *(const bf16x8*)p; }

DEV bf16x8 cvt8(const float* __restrict__ p){
  const float4* q = (const float4*)p;
  float4 v0 = q[0], v1 = q[1];
  bf16x8 r;
  r[0]=(short)bf16r(v0.x); r[1]=(short)bf16r(v0.y); r[2]=(short)bf16r(v0.z); r[3]=(short)bf16r(v0.w);
  r[4]=(short)bf16r(v1.x); r[5]=(short)bf16r(v1.y); r[6]=(short)bf16r(v1.z); r[7]=(short)bf16r(v1.w);
  return r;
}

// ---------------- prep: pack weights bf16; Wm/Wc -> per-wave reg-frag layout;
// h0 -> bf16 swizzled tile layout.
__global__ void k_prep(const float* __restrict__ d1w, const float* __restrict__ d2w,
                       const float* __restrict__ mWih, const float* __restrict__ mWhh,
                       const float* __restrict__ mbih, const float* __restrict__ mbhh,
                       const float* __restrict__ cWih, const float* __restrict__ cWhh,
                       const float* __restrict__ cbih, const float* __restrict__ cbhh,
                       const float* __restrict__ h0,
                       unsigned short* d1w_bf, unsigned short* d2w_bf,
                       unsigned short* Wm, unsigned short* Wc, float* bm, float* bc,
                       unsigned short* h0bf)
{
  const long long TOT = 16384 + 49152 + 655360 + 655360 + 2560 + 2560 + 10485760ll;
  for (long long i = (long long)blockIdx.x * 256 + threadIdx.x; i < TOT;
       i += (long long)gridDim.x * 256) {
    long long x = i;
    if (x < 16384) { d1w_bf[x] = bf16r(d1w[x]); continue; }
    x -= 16384;
    if (x < 49152) { d2w_bf[x] = bf16r(d2w[x]); continue; }
    x -= 49152;
    if (x < 655360) {
      int e    = (int)(x & 7);
      int lane = (int)((x >> 3) & 63);
      int kt   = (int)((x >> 9) & 7);
      int q    = (int)((x >> 12) & 3);
      int w    = (int)((x >> 14) & 7);
      int n    = (int)(x >> 17);
      int g = q * 128 + w * 16 + (lane & 15);
      int k = kt * 32 + (lane >> 4) * 8 + e;
      Wm[x] = bf16r(k < 128 ? mWih[((size_t)n * 512 + g) * 128 + k]
                            : mWhh[((size_t)n * 512 + g) * 128 + (k - 128)]);
      continue;
    }
    x -= 655360;
    if (x < 655360) {
      int e    = (int)(x & 7);
      int lane = (int)((x >> 3) & 63);
      int kt   = (int)((x >> 9) & 7);
      int q    = (int)((x >> 12) & 3);
      int w    = (int)((x >> 14) & 7);
      int l0   = (int)(x >> 17);
      int g = q * 128 + w * 16 + (lane & 15);
      int k = kt * 32 + (lane >> 4) * 8 + e;
      Wc[x] = bf16r(k < 128 ? cWih[((size_t)l0 * 512 + g) * 128 + k]
                            : cWhh[((size_t)l0 * 512 + g) * 128 + (k - 128)]);
      continue;
    }
    x -= 655360;
    if (x < 2560) { bm[x] = mbih[x] + mbhh[x]; continue; }
    x -= 2560;
    if (x < 2560) { bc[x] = cbih[x] + cbhh[x]; continue; }
    x -= 2560;
    {
      int d = (int)(x & 127);
      int b = (int)((x >> 7) & 16383);
      h0bf[(x - d) + (d ^ ((b & 7) << 3))] = bf16r(h0[x]);
    }
  }
}

// ---------------- fused obs-GEMM + mem-LSTM (W resident, c0 hoisted) ---------
__global__ __launch_bounds__(512) void k_memobs(const float* __restrict__ input,
                                                const unsigned short* __restrict__ d1w,
                                                const float* __restrict__ d1b,
                                                const unsigned short* __restrict__ h0bf,
                                                const float* __restrict__ c0,
                                                const unsigned short* __restrict__ Wmp,
                                                const float* __restrict__ bm,
                                                float* __restrict__ out_h,
                                                float* __restrict__ out_c,
                                                unsigned short* __restrict__ cat,
                                                unsigned short* __restrict__ obs_bf)
{
  __shared__ __align__(16) unsigned short os[64][128];  // 16 KB obs (swizzled)
  __shared__ __align__(16) unsigned short hb[64][128];  // 16 KB h0 tile (swizzled)
  __shared__ __align__(16) float hs[64][128];           // 32 KB h f32 staging
  __shared__ __align__(16) float cs[64][128];           // 32 KB c f32 staging

  const int n = blockIdx.x >> 8;
  const int b0 = (blockIdx.x & 255) << 6;
  const int tid = threadIdx.x;
  const int w = tid >> 6, lane = tid & 63;
  const int c0l = lane & 15, hi = lane >> 4;
  const int u = w * 16 + c0l;

  // DMA h0 tile (pre-swizzled in global) -> hb; drains at first barrier.
  {
    const unsigned short* src = h0bf + ((size_t)n * BB + b0) * DD;
    __builtin_amdgcn_global_load_lds((const unsigned int*)(src + tid * 8),
                                     (unsigned int*)((unsigned short*)hb + w * 512), 16, 0, 0);
    __builtin_amdgcn_global_load_lds((const unsigned int*)(src + 4096 + tid * 8),
                                     (unsigned int*)((unsigned short*)hb + 4096 + w * 512), 16, 0, 0);
  }

  // hoist c0 loads: 16 scalar loads issued EARLY, latency hidden under
  // wfr loads + obs GEMM (they sat on the epilogue critical path before).
  float cold[2][2][4];
  #pragma unroll
  for (int hh = 0; hh < 2; hh++)
    #pragma unroll
    for (int m2 = 0; m2 < 2; m2++)
      #pragma unroll
      for (int j = 0; j < 4; j++) {
        const int r = hh * 32 + m2 * 16 + hi * 4 + j;
        cold[hh][m2][j] = c0[((size_t)n * BB + b0 + r) * HH + u];
      }

  // mem W fragments (resident)
  const unsigned short* Wg = Wmp + (size_t)n * 131072 + (size_t)w * 16384 + lane * 8;
  bf16x8 wfr[4][8];
  #pragma unroll
  for (int q = 0; q < 4; q++)
    #pragma unroll
    for (int kt = 0; kt < 8; kt++)
      wfr[q][kt] = ld8(Wg + (q * 8 + kt) * 512);

  // ---- obs phase ----
  const float biasD = d1b[u];
  f32x4 oacc[4];
  #pragma unroll
  for (int mt = 0; mt < 4; mt++) oacc[mt] = (f32x4){biasD, biasD, biasD, biasD};

  #pragma unroll
  for (int kt = 0; kt < 4; ++kt) {
    const int k = kt * 32 + hi * 8;
    bf16x8 bfrD = ld8(d1w + (size_t)u * DD + k);
    #pragma unroll
    for (int mt = 0; mt < 4; mt++) {
      const int br = b0 + mt * 16 + c0l;
      bf16x8 a = cvt8(input + ((size_t)br * NAg + n) * DD + k);
      oacc[mt] = __builtin_amdgcn_mfma_f32_16x16x32_bf16(a, bfrD, oacc[mt], 0, 0, 0);
    }
  }
  #pragma unroll
  for (int mt = 0; mt < 4; mt++) {
    #pragma unroll
    for (int j = 0; j < 4; j++) {
      const int r = mt * 16 + hi * 4 + j;
      os[r][u ^ ((r & 7) << 3)] = bf16r(oacc[mt][j]);
    }
  }
  __syncthreads();   // certifies os AND drains h0 DMA
  // copy os -> obs_bf (linear; global stays swizzled for k_comf's DMA)
  #pragma unroll
  for (int cc = 0; cc < 2; ++cc) {
    const int idx = cc * 512 + tid;
    const int r = idx >> 4;
    const int c8 = (idx & 15) << 3;
    bf16x8 v = *(const bf16x8*)&os[r][c8];
    *(bf16x8*)(obs_bf + ((size_t)n * BB + b0 + r) * DD + c8) = v;
  }

  // ---- mem-LSTM phase ----
  const float bI = bm[n * G4 + u];
  const float bF = bm[n * G4 + 128 + u];
  const float bG = bm[n * G4 + 256 + u];
  const float bO = bm[n * G4 + 384 + u];

  #pragma unroll
  for (int hh = 0; hh < 2; hh++) {
    f32x4 acc[2][4];
    #pragma unroll
    for (int m2 = 0; m2 < 2; m2++) {
      acc[m2][0] = (f32x4){bI, bI, bI, bI};
      acc[m2][1] = (f32x4){bF, bF, bF, bF};
      acc[m2][2] = (f32x4){bG, bG, bG, bG};
      acc[m2][3] = (f32x4){bO, bO, bO, bO};
    }

    #pragma unroll
    for (int kt = 0; kt < 8; ++kt) {
      bf16x8 a[2];
      #pragma unroll
      for (int m2 = 0; m2 < 2; m2++) {
        const int r = (hh * 2 + m2) * 16 + c0l;
        if (kt < 4) a[m2] = ld8(&os[r][(kt * 32 + hi * 8) ^ ((r & 7) << 3)]);
        else        a[m2] = ld8(&hb[r][((kt - 4) * 32 + hi * 8) ^ ((r & 7) << 3)]);
      }
      #pragma unroll
      for (int m2 = 0; m2 < 2; m2++)
        #pragma unroll
        for (int q = 0; q < 4; q++)
          acc[m2][q] = __builtin_amdgcn_mfma_f32_16x16x32_bf16(a[m2], wfr[q][kt], acc[m2][q], 0, 0, 0);
    }

    #pragma unroll
    for (int m2 = 0; m2 < 2; m2++) {
      #pragma unroll
      for (int j = 0; j < 4; j++) {
        const int r = hh * 32 + m2 * 16 + hi * 4 + j;
        float cn, hn;
        lstm_cell(acc[m2][0][j], acc[m2][1][j], acc[m2][2][j], acc[m2][3][j],
                  cold[hh][m2][j], cn, hn);
        const int sc = u ^ ((r & 7) << 3);
        hs[r][sc] = hn;
        cs[r][sc] = cn;
      }
    }
  }
  __syncthreads();
  // out_h copy (float4, full lines)
  #pragma unroll
  for (int cc = 0; cc < 4; ++cc) {
    const int idx = cc * 512 + tid;
    const int r = idx >> 5;
    const int c4 = (idx & 31) << 2;
    float4 v = *(const float4*)&hs[r][c4 ^ ((r & 7) << 3)];
    *(float4*)(out_h + ((size_t)n * BB + b0 + r) * HH + c4) = v;
  }
  // out_c copy
  #pragma unroll
  for (int cc = 0; cc < 4; ++cc) {
    const int idx = cc * 512 + tid;
    const int r = idx >> 5;
    const int c4 = (idx & 31) << 2;
    float4 v = *(const float4*)&cs[r][c4 ^ ((r & 7) << 3)];
    *(float4*)(out_c + ((size_t)n * BB + b0 + r) * HH + c4) = v;
  }
  // cat copy (bf16x8, full lines)
  #pragma unroll
  for (int cc = 0; cc < 2; ++cc) {
    const int idx = cc * 512 + tid;
    const int r = idx >> 4;
    const int c8 = (idx & 15) << 3;
    const float* p = &hs[r][c8 ^ ((r & 7) << 3)];
    float4 v0 = *(const float4*)p, v1 = *(const float4*)(p + 4);
    bf16x8 bv;
    bv[0]=(short)bf16r(v0.x); bv[1]=(short)bf16r(v0.y); bv[2]=(short)bf16r(v0.z); bv[3]=(short)bf16r(v0.w);
    bv[4]=(short)bf16r(v1.x); bv[5]=(short)bf16r(v1.y); bv[6]=(short)bf16r(v1.z); bv[7]=(short)bf16r(v1.w);
    *(bf16x8*)(cat + ((size_t)n * BB + b0 + r) * CATW + 640 + c8) = bv;
  }
}

// ---------------- fused com scan: reg-W + obs LDS prefetch + t0-skip ---------
__global__ __launch_bounds__(512) void k_comf(const unsigned short* __restrict__ obs_bf,
                                              const unsigned short* __restrict__ Wpk,
                                              const float* __restrict__ bc,
                                              unsigned short* __restrict__ cat)
{
  __shared__ __align__(16) unsigned short hl[2][64][128];   // 32 KB
  __shared__ __align__(16) unsigned short ol[2][64][128];   // 32 KB obs dbuf

  const int bid = blockIdx.x;
  const int swz = (bid & 7) * 160 + (bid >> 3);   // 1280 = 8*160, bijective
  const int l0 = swz >> 8;
  const int b0 = (swz & 255) << 6;
  const int tid = threadIdx.x;
  const int w = tid >> 6, lane = tid & 63;
  const int c0l = lane & 15, hi = lane >> 4;
  const int u = w * 16 + c0l;

  const unsigned short* Wg = Wpk + (size_t)l0 * 131072 + (size_t)w * 16384 + lane * 8;
  bf16x8 wfr[4][8];
  #pragma unroll
  for (int q = 0; q < 4; q++)
    #pragma unroll
    for (int kt = 0; kt < 8; kt++)
      wfr[q][kt] = ld8(Wg + (q * 8 + kt) * 512);

  const float bI = bc[l0 * G4 + u];
  const float bF = bc[l0 * G4 + 128 + u];
  const float bG = bc[l0 * G4 + 256 + u];
  const float bO = bc[l0 * G4 + 384 + u];

  // prologue DMA: obs tile of step 0 -> ol[0]; per-wave LDS base + w*512
  {
    const int it0 = (0 >= l0 ? 1 : 0);
    const unsigned short* src = obs_bf + ((size_t)it0 * BB + b0) * DD;
    __builtin_amdgcn_global_load_lds((const unsigned int*)(src + tid * 8),
                                     (unsigned int*)((unsigned short*)ol + w * 512), 16, 0, 0);
    __builtin_amdgcn_global_load_lds((const unsigned int*)(src + 4096 + tid * 8),
                                     (unsigned int*)((unsigned short*)ol + 4096 + w * 512), 16, 0, 0);
  }
  __syncthreads();

  float creg[2][2][4];
  #pragma unroll
  for (int hh = 0; hh < 2; hh++)
    #pragma unroll
    for (int m2 = 0; m2 < 2; m2++)
      #pragma unroll
      for (int j = 0; j < 4; j++) creg[hh][m2][j] = 0.0f;

  for (int t = 0; t < 5; ++t) {
    const int it = (t == 4) ? l0 : (t + (t >= l0 ? 1 : 0));
    const int rbuf = (t + 1) & 1, wbuf = t & 1;
    const int ob_c = t & 1, ob_n = (t + 1) & 1;

    if (t < 4) {
      const int tn = t + 1;
      const int itn = (tn == 4) ? l0 : (tn + (tn >= l0 ? 1 : 0));
      const unsigned short* src = obs_bf + ((size_t)itn * BB + b0) * DD;
      unsigned short* dst = (unsigned short*)ol + ob_n * 8192 + w * 512;
      __builtin_amdgcn_global_load_lds((const unsigned int*)(src + tid * 8),
                                       (unsigned int*)dst, 16, 0, 0);
      __builtin_amdgcn_global_load_lds((const unsigned int*)(src + 4096 + tid * 8),
                                       (unsigned int*)(dst + 4096), 16, 0, 0);
    }

    #pragma unroll
    for (int hh = 0; hh < 2; hh++) {
      f32x4 acc[2][4];
      #pragma unroll
      for (int m2 = 0; m2 < 2; m2++) {
        acc[m2][0] = (f32x4){bI, bI, bI, bI};
        acc[m2][1] = (f32x4){bF, bF, bF, bF};
        acc[m2][2] = (f32x4){bG, bG, bG, bG};
        acc[m2][3] = (f32x4){bO, bO, bO, bO};
      }

      #pragma unroll
      for (int kt = 0; kt < 4; ++kt) {
        bf16x8 a[2];
        #pragma unroll
        for (int m2 = 0; m2 < 2; m2++) {
          const int r = (hh * 2 + m2) * 16 + c0l;
          a[m2] = ld8(&ol[ob_c][r][(kt * 32 + hi * 8) ^ ((r & 7) << 3)]);
        }
        #pragma unroll
        for (int m2 = 0; m2 < 2; m2++)
          #pragma unroll
          for (int q = 0; q < 4; q++)
            acc[m2][q] = __builtin_amdgcn_mfma_f32_16x16x32_bf16(a[m2], wfr[q][kt], acc[m2][q], 0, 0, 0);
      }

      if (hh == 0) __syncthreads();   // hl[rbuf] from step t-1 certified

      // h-part: skipped at t=0 (h = 0)
      if (t > 0) {
        #pragma unroll
        for (int kt = 4; kt < 8; ++kt) {
          bf16x8 a[2];
          #pragma unroll
          for (int m2 = 0; m2 < 2; m2++) {
            const int r = (hh * 2 + m2) * 16 + c0l;
            a[m2] = ld8(&hl[rbuf][r][((kt - 4) * 32 + hi * 8) ^ ((r & 7) << 3)]);
          }
          #pragma unroll
          for (int m2 = 0; m2 < 2; m2++)
            #pragma unroll
            for (int q = 0; q < 4; q++)
              acc[m2][q] = __builtin_amdgcn_mfma_f32_16x16x32_bf16(a[m2], wfr[q][kt], acc[m2][q], 0, 0, 0);
        }
      }

      #pragma unroll
      for (int m2 = 0; m2 < 2; m2++) {
        #pragma unroll
        for (int j = 0; j < 4; j++) {
          const int r = hh * 32 + m2 * 16 + hi * 4 + j;
          float cn, hn;
          lstm_cell(acc[m2][0][j], acc[m2][1][j], acc[m2][2][j], acc[m2][3][j],
                    creg[hh][m2][j], cn, hn);
          creg[hh][m2][j] = cn;
          hl[wbuf][r][u ^ ((r & 7) << 3)] = bf16r(hn);
        }
      }
    }
    __syncthreads();

    unsigned short* catb = cat + ((size_t)it * BB + b0) * CATW + l0 * 128;
    #pragma unroll
    for (int cc = 0; cc < 2; ++cc) {
      const int idx = cc * 512 + tid;
      const int r = idx >> 4;
      const int c8 = (idx & 15) << 3;
      bf16x8 v = *(const bf16x8*)&hl[wbuf][r][c8 ^ ((r & 7) << 3)];
      *(bf16x8*)(catb + (size_t)r * CATW + c8) = v;
    }
  }
}

// ---------------- outs = cat @ d2_w^T + d2_b, 256 rows/block (4 m-tiles) -----
__global__ __launch_bounds__(256) void k_d2(const unsigned short* __restrict__ cat,
                                            const unsigned short* __restrict__ d2w,
                                            const float* __restrict__ d2b,
                                            float* __restrict__ out)
{
  const int m0 = blockIdx.x * 256;
  const int w = threadIdx.x >> 6, l = threadIdx.x & 63;
  const int c0l = l & 15, hi = l >> 4;

  const unsigned short* arow[4];
  #pragma unroll
  for (int mt = 0; mt < 4; mt++)
    arow[mt] = cat + (size_t)(m0 + mt * 64 + w * 16 + c0l) * CATW;

  f32x4 acc[4][4];
  #pragma unroll
  for (int mt = 0; mt < 4; mt++)
    #pragma unroll
    for (int nt = 0; nt < 4; nt++) acc[mt][nt] = (f32x4){0, 0, 0, 0};

  #pragma unroll 4
  for (int kt = 0; kt < 24; ++kt) {
    const int k = kt * 32 + hi * 8;
    bf16x8 bfr[4];
    #pragma unroll
    for (int nt = 0; nt < 4; nt++)
      bfr[nt] = ld8(d2w + (size_t)(nt * 16 + c0l) * CATW + k);
    #pragma unroll
    for (int mt = 0; mt < 4; mt++) {
      bf16x8 a = ld8(arow[mt] + k);
      #pragma unroll
      for (int nt = 0; nt < 4; nt++)
        acc[mt][nt] = __builtin_amdgcn_mfma_f32_16x16x32_bf16(a, bfr[nt], acc[mt][nt], 0, 0, 0);
    }
  }
  #pragma unroll
  for (int mt = 0; mt < 4; mt++) {
    #pragma unroll
    for (int nt = 0; nt < 4; nt++) {
      const int col = nt * 16 + c0l;
      const float bias = d2b[col];
      #pragma unroll
      for (int j = 0; j < 4; j++) {
        const int r = m0 + mt * 64 + w * 16 + hi * 4 + j;
        out[(size_t)r * AA + col] = acc[mt][nt][j] + bias;
      }
    }
  }
}

extern "C" void kernel_launch(void* const* d_in, const int* in_sizes, int n_in,
                              void* d_out, int out_size, void* d_ws, size_t ws_size,
                              hipStream_t stream)
{
  const float* input = (const float*)d_in[0];
  const float* h0    = (const float*)d_in[1];
  const float* c0    = (const float*)d_in[2];
  const float* d1w   = (const float*)d_in[3];
  const float* d1b   = (const float*)d_in[4];
  const float* d2w   = (const float*)d_in[5];
  const float* d2b   = (const float*)d_in[6];
  const float* mWih  = (const float*)d_in[7];
  const float* mWhh  = (const float*)d_in[8];
  const float* mbih  = (const float*)d_in[9];
  const float* mbhh  = (const float*)d_in[10];
  const float* cWih  = (const float*)d_in[11];
  const float* cWhh  = (const float*)d_in[12];
  const float* cbih  = (const float*)d_in[13];
  const float* cbhh  = (const float*)d_in[14];
  float* out = (float*)d_out;

  char* ws = (char*)d_ws;
  size_t off = 0;
  auto alloc = [&](size_t bytes) { void* p = ws + off; off += (bytes + 255) & ~255ull; return p; };
  unsigned short* d1w_bf = (unsigned short*)alloc(16384 * 2);
  unsigned short* d2w_bf = (unsigned short*)alloc(49152 * 2);
  unsigned short* Wm     = (unsigned short*)alloc(655360 * 2);
  unsigned short* Wcb    = (unsigned short*)alloc(655360 * 2);
  float* bm              = (float*)alloc(2560 * 4);
  float* bc              = (float*)alloc(2560 * 4);
  unsigned short* obs_bf = (unsigned short*)alloc((size_t)NAg * BB * DD * 2);
  unsigned short* cat    = (unsigned short*)alloc((size_t)NAg * BB * CATW * 2);
  unsigned short* h0bf   = (unsigned short*)alloc((size_t)NAg * BB * DD * 2);

  float* out_h = out + (size_t)NAg * BB * AA;
  float* out_c = out_h + (size_t)NAg * BB * HH;

  k_prep<<<2048, 256, 0, stream>>>(d1w, d2w, mWih, mWhh, mbih, mbhh,
                                   cWih, cWhh, cbih, cbhh, h0,
                                   d1w_bf, d2w_bf, Wm, Wcb, bm, bc, h0bf);
  k_memobs<<<(NAg * BB) / 64, 512, 0, stream>>>(input, d1w_bf, d1b, h0bf, c0, Wm, bm,
                                                out_h, out_c, cat, obs_bf);
  k_comf<<<(NAg * BB) / 64, 512, 0, stream>>>(obs_bf, Wcb, bc, cat);
  k_d2<<<(NAg * BB) / 256, 256, 0, stream>>>(cat, d2w_bf, d2b, out);
}

// Round 24
// 294.289 us; speedup vs baseline: 1.1851x; 1.0492x over previous
//
#include <hip/hip_runtime.h>

#define BB   16384
#define NAg  5
#define DD   128
#define HH   128
#define G4   512   // 4*H
#define KC   256   // LS1 + H
#define AA   64
#define CATW 768   // 6*H
#define L2E  1.4426950408889634f

typedef __attribute__((ext_vector_type(8))) short bf16x8;
typedef __attribute__((ext_vector_type(4))) float f32x4;

#define DEV static __device__ __forceinline__

DEV unsigned short bf16r(float x){
  unsigned u = __float_as_uint(x);
  unsigned r = (u + 0x7fffu + ((u >> 16) & 1u)) >> 16;
  return (unsigned short)r;
}
DEV float rcpf(float x){ return __builtin_amdgcn_rcpf(x); }
DEV float ex2(float x){ return __builtin_amdgcn_exp2f(x); }

// gates arrive PRE-SCALED: i,f,o by log2e; g by 2*log2e.
// sig(x) -> rcp(1+2^-xs); tanh(g) -> (1-2^-gs)*rcp(1+2^-gs)
DEV void lstm_cell(float iv, float fv, float gv, float ov, float cold,
                   float& cn, float& hn){
  float ef = ex2(-fv), ei = ex2(-iv), eg = ex2(-gv);
  cn = cold * rcpf(1.0f + ef) + (1.0f - eg) * rcpf((1.0f + ei) * (1.0f + eg));
  float eo = ex2(-ov), ec = ex2(-2.0f * L2E * cn);
  hn = (1.0f - ec) * rcpf((1.0f + eo) * (1.0f + ec));
}

DEV bf16x8 ld8(const unsigned short* p){ return *(const bf16x8*)p; }

DEV bf16x8 cvt8(const float* __restrict__ p){
  const float4* q = (const float4*)p;
  float4 v0 = q[0], v1 = q[1];
  bf16x8 r;
  r[0]=(short)bf16r(v0.x); r[1]=(short)bf16r(v0.y); r[2]=(short)bf16r(v0.z); r[3]=(short)bf16r(v0.w);
  r[4]=(short)bf16r(v1.x); r[5]=(short)bf16r(v1.y); r[6]=(short)bf16r(v1.z); r[7]=(short)bf16r(v1.w);
  return r;
}

// ---------------- prep: pack weights bf16 (gate pre-scaled); h0 -> bf16 swz --
__global__ void k_prep(const float* __restrict__ d1w, const float* __restrict__ d2w,
                       const float* __restrict__ mWih, const float* __restrict__ mWhh,
                       const float* __restrict__ mbih, const float* __restrict__ mbhh,
                       const float* __restrict__ cWih, const float* __restrict__ cWhh,
                       const float* __restrict__ cbih, const float* __restrict__ cbhh,
                       const float* __restrict__ h0,
                       unsigned short* d1w_bf, unsigned short* d2w_bf,
                       unsigned short* Wm, unsigned short* Wc, float* bm, float* bc,
                       unsigned short* h0bf)
{
  const long long TOT = 16384 + 49152 + 655360 + 655360 + 2560 + 2560 + 10485760ll;
  for (long long i = (long long)blockIdx.x * 256 + threadIdx.x; i < TOT;
       i += (long long)gridDim.x * 256) {
    long long x = i;
    if (x < 16384) { d1w_bf[x] = bf16r(d1w[x]); continue; }
    x -= 16384;
    if (x < 49152) { d2w_bf[x] = bf16r(d2w[x]); continue; }
    x -= 49152;
    if (x < 655360) {
      int e    = (int)(x & 7);
      int lane = (int)((x >> 3) & 63);
      int kt   = (int)((x >> 9) & 7);
      int q    = (int)((x >> 12) & 3);
      int w    = (int)((x >> 14) & 7);
      int n    = (int)(x >> 17);
      int g = q * 128 + w * 16 + (lane & 15);
      int k = kt * 32 + (lane >> 4) * 8 + e;
      const float sc = (q == 2) ? (2.0f * L2E) : L2E;
      Wm[x] = bf16r(sc * (k < 128 ? mWih[((size_t)n * 512 + g) * 128 + k]
                                  : mWhh[((size_t)n * 512 + g) * 128 + (k - 128)]));
      continue;
    }
    x -= 655360;
    if (x < 655360) {
      int e    = (int)(x & 7);
      int lane = (int)((x >> 3) & 63);
      int kt   = (int)((x >> 9) & 7);
      int q    = (int)((x >> 12) & 3);
      int w    = (int)((x >> 14) & 7);
      int l0   = (int)(x >> 17);
      int g = q * 128 + w * 16 + (lane & 15);
      int k = kt * 32 + (lane >> 4) * 8 + e;
      const float sc = (q == 2) ? (2.0f * L2E) : L2E;
      Wc[x] = bf16r(sc * (k < 128 ? cWih[((size_t)l0 * 512 + g) * 128 + k]
                                  : cWhh[((size_t)l0 * 512 + g) * 128 + (k - 128)]));
      continue;
    }
    x -= 655360;
    if (x < 2560) {
      int gate = ((int)x & 511) >> 7;
      const float sc = (gate == 2) ? (2.0f * L2E) : L2E;
      bm[x] = sc * (mbih[x] + mbhh[x]);
      continue;
    }
    x -= 2560;
    if (x < 2560) {
      int gate = ((int)x & 511) >> 7;
      const float sc = (gate == 2) ? (2.0f * L2E) : L2E;
      bc[x] = sc * (cbih[x] + cbhh[x]);
      continue;
    }
    x -= 2560;
    {
      int d = (int)(x & 127);
      int b = (int)((x >> 7) & 16383);
      h0bf[(x - d) + (d ^ ((b & 7) << 3))] = bf16r(h0[x]);
    }
  }
}

// ---------------- fused obs-GEMM + mem-LSTM (W resident, c0 hoisted) ---------
__global__ __launch_bounds__(512) void k_memobs(const float* __restrict__ input,
                                                const unsigned short* __restrict__ d1w,
                                                const float* __restrict__ d1b,
                                                const unsigned short* __restrict__ h0bf,
                                                const float* __restrict__ c0,
                                                const unsigned short* __restrict__ Wmp,
                                                const float* __restrict__ bm,
                                                float* __restrict__ out_h,
                                                float* __restrict__ out_c,
                                                unsigned short* __restrict__ cat,
                                                unsigned short* __restrict__ obs_bf)
{
  __shared__ __align__(16) unsigned short os[64][128];  // 16 KB obs (swizzled)
  __shared__ __align__(16) unsigned short hb[64][128];  // 16 KB h0 tile (swizzled)
  __shared__ __align__(16) float hs[64][128];           // 32 KB h f32 staging
  __shared__ __align__(16) float cs[64][128];           // 32 KB c f32 staging

  const int n = blockIdx.x >> 8;
  const int b0 = (blockIdx.x & 255) << 6;
  const int tid = threadIdx.x;
  const int w = tid >> 6, lane = tid & 63;
  const int c0l = lane & 15, hi = lane >> 4;
  const int u = w * 16 + c0l;

  // DMA h0 tile -> hb; drains at first barrier.
  {
    const unsigned short* src = h0bf + ((size_t)n * BB + b0) * DD;
    __builtin_amdgcn_global_load_lds((const unsigned int*)(src + tid * 8),
                                     (unsigned int*)((unsigned short*)hb + w * 512), 16, 0, 0);
    __builtin_amdgcn_global_load_lds((const unsigned int*)(src + 4096 + tid * 8),
                                     (unsigned int*)((unsigned short*)hb + 4096 + w * 512), 16, 0, 0);
  }

  // hoist c0 loads early (latency hidden under wfr + obs GEMM)
  float cold[2][2][4];
  #pragma unroll
  for (int hh = 0; hh < 2; hh++)
    #pragma unroll
    for (int m2 = 0; m2 < 2; m2++)
      #pragma unroll
      for (int j = 0; j < 4; j++) {
        const int r = hh * 32 + m2 * 16 + hi * 4 + j;
        cold[hh][m2][j] = c0[((size_t)n * BB + b0 + r) * HH + u];
      }

  // mem W fragments (resident)
  const unsigned short* Wg = Wmp + (size_t)n * 131072 + (size_t)w * 16384 + lane * 8;
  bf16x8 wfr[4][8];
  #pragma unroll
  for (int q = 0; q < 4; q++)
    #pragma unroll
    for (int kt = 0; kt < 8; kt++)
      wfr[q][kt] = ld8(Wg + (q * 8 + kt) * 512);

  // ---- obs phase ----
  const float biasD = d1b[u];
  f32x4 oacc[4];
  #pragma unroll
  for (int mt = 0; mt < 4; mt++) oacc[mt] = (f32x4){biasD, biasD, biasD, biasD};

  #pragma unroll
  for (int kt = 0; kt < 4; ++kt) {
    const int k = kt * 32 + hi * 8;
    bf16x8 bfrD = ld8(d1w + (size_t)u * DD + k);
    #pragma unroll
    for (int mt = 0; mt < 4; mt++) {
      const int br = b0 + mt * 16 + c0l;
      bf16x8 a = cvt8(input + ((size_t)br * NAg + n) * DD + k);
      oacc[mt] = __builtin_amdgcn_mfma_f32_16x16x32_bf16(a, bfrD, oacc[mt], 0, 0, 0);
    }
  }
  #pragma unroll
  for (int mt = 0; mt < 4; mt++) {
    #pragma unroll
    for (int j = 0; j < 4; j++) {
      const int r = mt * 16 + hi * 4 + j;
      os[r][u ^ ((r & 7) << 3)] = bf16r(oacc[mt][j]);
    }
  }
  __syncthreads();   // certifies os AND drains h0 DMA
  #pragma unroll
  for (int cc = 0; cc < 2; ++cc) {
    const int idx = cc * 512 + tid;
    const int r = idx >> 4;
    const int c8 = (idx & 15) << 3;
    bf16x8 v = *(const bf16x8*)&os[r][c8];
    *(bf16x8*)(obs_bf + ((size_t)n * BB + b0 + r) * DD + c8) = v;
  }

  // ---- mem-LSTM phase ----
  const float bI = bm[n * G4 + u];
  const float bF = bm[n * G4 + 128 + u];
  const float bG = bm[n * G4 + 256 + u];
  const float bO = bm[n * G4 + 384 + u];

  #pragma unroll
  for (int hh = 0; hh < 2; hh++) {
    f32x4 acc[2][4];
    #pragma unroll
    for (int m2 = 0; m2 < 2; m2++) {
      acc[m2][0] = (f32x4){bI, bI, bI, bI};
      acc[m2][1] = (f32x4){bF, bF, bF, bF};
      acc[m2][2] = (f32x4){bG, bG, bG, bG};
      acc[m2][3] = (f32x4){bO, bO, bO, bO};
    }

    #pragma unroll
    for (int kt = 0; kt < 8; ++kt) {
      bf16x8 a[2];
      #pragma unroll
      for (int m2 = 0; m2 < 2; m2++) {
        const int r = (hh * 2 + m2) * 16 + c0l;
        if (kt < 4) a[m2] = ld8(&os[r][(kt * 32 + hi * 8) ^ ((r & 7) << 3)]);
        else        a[m2] = ld8(&hb[r][((kt - 4) * 32 + hi * 8) ^ ((r & 7) << 3)]);
      }
      #pragma unroll
      for (int m2 = 0; m2 < 2; m2++)
        #pragma unroll
        for (int q = 0; q < 4; q++)
          acc[m2][q] = __builtin_amdgcn_mfma_f32_16x16x32_bf16(a[m2], wfr[q][kt], acc[m2][q], 0, 0, 0);
    }

    #pragma unroll
    for (int m2 = 0; m2 < 2; m2++) {
      #pragma unroll
      for (int j = 0; j < 4; j++) {
        const int r = hh * 32 + m2 * 16 + hi * 4 + j;
        float cn, hn;
        lstm_cell(acc[m2][0][j], acc[m2][1][j], acc[m2][2][j], acc[m2][3][j],
                  cold[hh][m2][j], cn, hn);
        const int sc = u ^ ((r & 7) << 3);
        hs[r][sc] = hn;
        cs[r][sc] = cn;
      }
    }
  }
  __syncthreads();
  #pragma unroll
  for (int cc = 0; cc < 4; ++cc) {
    const int idx = cc * 512 + tid;
    const int r = idx >> 5;
    const int c4 = (idx & 31) << 2;
    float4 v = *(const float4*)&hs[r][c4 ^ ((r & 7) << 3)];
    *(float4*)(out_h + ((size_t)n * BB + b0 + r) * HH + c4) = v;
  }
  #pragma unroll
  for (int cc = 0; cc < 4; ++cc) {
    const int idx = cc * 512 + tid;
    const int r = idx >> 5;
    const int c4 = (idx & 31) << 2;
    float4 v = *(const float4*)&cs[r][c4 ^ ((r & 7) << 3)];
    *(float4*)(out_c + ((size_t)n * BB + b0 + r) * HH + c4) = v;
  }
  #pragma unroll
  for (int cc = 0; cc < 2; ++cc) {
    const int idx = cc * 512 + tid;
    const int r = idx >> 4;
    const int c8 = (idx & 15) << 3;
    const float* p = &hs[r][c8 ^ ((r & 7) << 3)];
    float4 v0 = *(const float4*)p, v1 = *(const float4*)(p + 4);
    bf16x8 bv;
    bv[0]=(short)bf16r(v0.x); bv[1]=(short)bf16r(v0.y); bv[2]=(short)bf16r(v0.z); bv[3]=(short)bf16r(v0.w);
    bv[4]=(short)bf16r(v1.x); bv[5]=(short)bf16r(v1.y); bv[6]=(short)bf16r(v1.z); bv[7]=(short)bf16r(v1.w);
    *(bf16x8*)(cat + ((size_t)n * BB + b0 + r) * CATW + 640 + c8) = bv;
  }
}

// ---------------- fused com scan: reg-W + obs LDS prefetch + t0-skip ---------
__global__ __launch_bounds__(512) void k_comf(const unsigned short* __restrict__ obs_bf,
                                              const unsigned short* __restrict__ Wpk,
                                              const float* __restrict__ bc,
                                              unsigned short* __restrict__ cat)
{
  __shared__ __align__(16) unsigned short hl[2][64][128];   // 32 KB
  __shared__ __align__(16) unsigned short ol[2][64][128];   // 32 KB obs dbuf

  const int bid = blockIdx.x;
  const int swz = (bid & 7) * 160 + (bid >> 3);   // 1280 = 8*160, bijective
  const int l0 = swz >> 8;
  const int b0 = (swz & 255) << 6;
  const int tid = threadIdx.x;
  const int w = tid >> 6, lane = tid & 63;
  const int c0l = lane & 15, hi = lane >> 4;
  const int u = w * 16 + c0l;

  const unsigned short* Wg = Wpk + (size_t)l0 * 131072 + (size_t)w * 16384 + lane * 8;
  bf16x8 wfr[4][8];
  #pragma unroll
  for (int q = 0; q < 4; q++)
    #pragma unroll
    for (int kt = 0; kt < 8; kt++)
      wfr[q][kt] = ld8(Wg + (q * 8 + kt) * 512);

  const float bI = bc[l0 * G4 + u];
  const float bF = bc[l0 * G4 + 128 + u];
  const float bG = bc[l0 * G4 + 256 + u];
  const float bO = bc[l0 * G4 + 384 + u];

  // prologue DMA: obs tile of step 0 -> ol[0]
  {
    const int it0 = (0 >= l0 ? 1 : 0);
    const unsigned short* src = obs_bf + ((size_t)it0 * BB + b0) * DD;
    __builtin_amdgcn_global_load_lds((const unsigned int*)(src + tid * 8),
                                     (unsigned int*)((unsigned short*)ol + w * 512), 16, 0, 0);
    __builtin_amdgcn_global_load_lds((const unsigned int*)(src + 4096 + tid * 8),
                                     (unsigned int*)((unsigned short*)ol + 4096 + w * 512), 16, 0, 0);
  }
  __syncthreads();

  float creg[2][2][4];
  #pragma unroll
  for (int hh = 0; hh < 2; hh++)
    #pragma unroll
    for (int m2 = 0; m2 < 2; m2++)
      #pragma unroll
      for (int j = 0; j < 4; j++) creg[hh][m2][j] = 0.0f;

  #pragma unroll
  for (int t = 0; t < 5; ++t) {
    const int it = (t == 4) ? l0 : (t + (t >= l0 ? 1 : 0));
    const int rbuf = (t + 1) & 1, wbuf = t & 1;
    const int ob_c = t & 1, ob_n = (t + 1) & 1;

    if (t < 4) {
      const int tn = t + 1;
      const int itn = (tn == 4) ? l0 : (tn + (tn >= l0 ? 1 : 0));
      const unsigned short* src = obs_bf + ((size_t)itn * BB + b0) * DD;
      unsigned short* dst = (unsigned short*)ol + ob_n * 8192 + w * 512;
      __builtin_amdgcn_global_load_lds((const unsigned int*)(src + tid * 8),
                                       (unsigned int*)dst, 16, 0, 0);
      __builtin_amdgcn_global_load_lds((const unsigned int*)(src + 4096 + tid * 8),
                                       (unsigned int*)(dst + 4096), 16, 0, 0);
    }

    #pragma unroll
    for (int hh = 0; hh < 2; hh++) {
      f32x4 acc[2][4];
      #pragma unroll
      for (int m2 = 0; m2 < 2; m2++) {
        acc[m2][0] = (f32x4){bI, bI, bI, bI};
        acc[m2][1] = (f32x4){bF, bF, bF, bF};
        acc[m2][2] = (f32x4){bG, bG, bG, bG};
        acc[m2][3] = (f32x4){bO, bO, bO, bO};
      }

      #pragma unroll
      for (int kt = 0; kt < 4; ++kt) {
        bf16x8 a[2];
        #pragma unroll
        for (int m2 = 0; m2 < 2; m2++) {
          const int r = (hh * 2 + m2) * 16 + c0l;
          a[m2] = ld8(&ol[ob_c][r][(kt * 32 + hi * 8) ^ ((r & 7) << 3)]);
        }
        #pragma unroll
        for (int m2 = 0; m2 < 2; m2++)
          #pragma unroll
          for (int q = 0; q < 4; q++)
            acc[m2][q] = __builtin_amdgcn_mfma_f32_16x16x32_bf16(a[m2], wfr[q][kt], acc[m2][q], 0, 0, 0);
      }

      if (hh == 0) __syncthreads();   // hl[rbuf] from step t-1 certified

      if (t > 0) {
        #pragma unroll
        for (int kt = 4; kt < 8; ++kt) {
          bf16x8 a[2];
          #pragma unroll
          for (int m2 = 0; m2 < 2; m2++) {
            const int r = (hh * 2 + m2) * 16 + c0l;
            a[m2] = ld8(&hl[rbuf][r][((kt - 4) * 32 + hi * 8) ^ ((r & 7) << 3)]);
          }
          #pragma unroll
          for (int m2 = 0; m2 < 2; m2++)
            #pragma unroll
            for (int q = 0; q < 4; q++)
              acc[m2][q] = __builtin_amdgcn_mfma_f32_16x16x32_bf16(a[m2], wfr[q][kt], acc[m2][q], 0, 0, 0);
        }
      }

      #pragma unroll
      for (int m2 = 0; m2 < 2; m2++) {
        #pragma unroll
        for (int j = 0; j < 4; j++) {
          const int r = hh * 32 + m2 * 16 + hi * 4 + j;
          float cn, hn;
          lstm_cell(acc[m2][0][j], acc[m2][1][j], acc[m2][2][j], acc[m2][3][j],
                    creg[hh][m2][j], cn, hn);
          creg[hh][m2][j] = cn;
          hl[wbuf][r][u ^ ((r & 7) << 3)] = bf16r(hn);
        }
      }
    }
    __syncthreads();

    unsigned short* catb = cat + ((size_t)it * BB + b0) * CATW + l0 * 128;
    #pragma unroll
    for (int cc = 0; cc < 2; ++cc) {
      const int idx = cc * 512 + tid;
      const int r = idx >> 4;
      const int c8 = (idx & 15) << 3;
      bf16x8 v = *(const bf16x8*)&hl[wbuf][r][c8 ^ ((r & 7) << 3)];
      *(bf16x8*)(catb + (size_t)r * CATW + c8) = v;
    }
  }
}

// ---------------- outs = cat @ d2_w^T + d2_b, 256 rows/block -----------------
__global__ __launch_bounds__(256) void k_d2(const unsigned short* __restrict__ cat,
                                            const unsigned short* __restrict__ d2w,
                                            const float* __restrict__ d2b,
                                            float* __restrict__ out)
{
  const int m0 = blockIdx.x * 256;
  const int w = threadIdx.x >> 6, l = threadIdx.x & 63;
  const int c0l = l & 15, hi = l >> 4;

  const unsigned short* arow[4];
  #pragma unroll
  for (int mt = 0; mt < 4; mt++)
    arow[mt] = cat + (size_t)(m0 + mt * 64 + w * 16 + c0l) * CATW;

  f32x4 acc[4][4];
  #pragma unroll
  for (int mt = 0; mt < 4; mt++)
    #pragma unroll
    for (int nt = 0; nt < 4; nt++) acc[mt][nt] = (f32x4){0, 0, 0, 0};

  #pragma unroll 4
  for (int kt = 0; kt < 24; ++kt) {
    const int k = kt * 32 + hi * 8;
    bf16x8 bfr[4];
    #pragma unroll
    for (int nt = 0; nt < 4; nt++)
      bfr[nt] = ld8(d2w + (size_t)(nt * 16 + c0l) * CATW + k);
    #pragma unroll
    for (int mt = 0; mt < 4; mt++) {
      bf16x8 a = ld8(arow[mt] + k);
      #pragma unroll
      for (int nt = 0; nt < 4; nt++)
        acc[mt][nt] = __builtin_amdgcn_mfma_f32_16x16x32_bf16(a, bfr[nt], acc[mt][nt], 0, 0, 0);
    }
  }
  #pragma unroll
  for (int mt = 0; mt < 4; mt++) {
    #pragma unroll
    for (int nt = 0; nt < 4; nt++) {
      const int col = nt * 16 + c0l;
      const float bias = d2b[col];
      #pragma unroll
      for (int j = 0; j < 4; j++) {
        const int r = m0 + mt * 64 + w * 16 + hi * 4 + j;
        out[(size_t)r * AA + col] = acc[mt][nt][j] + bias;
      }
    }
  }
}

extern "C" void kernel_launch(void* const* d_in, const int* in_sizes, int n_in,
                              void* d_out, int out_size, void* d_ws, size_t ws_size,
                              hipStream_t stream)
{
  const float* input = (const float*)d_in[0];
  const float* h0    = (const float*)d_in[1];
  const float* c0    = (const float*)d_in[2];
  const float* d1w   = (const float*)d_in[3];
  const float* d1b   = (const float*)d_in[4];
  const float* d2w   = (const float*)d_in[5];
  const float* d2b   = (const float*)d_in[6];
  const float* mWih  = (const float*)d_in[7];
  const float* mWhh  = (const float*)d_in[8];
  const float* mbih  = (const float*)d_in[9];
  const float* mbhh  = (const float*)d_in[10];
  const float* cWih  = (const float*)d_in[11];
  const float* cWhh  = (const float*)d_in[12];
  const float* cbih  = (const float*)d_in[13];
  const float* cbhh  = (const float*)d_in[14];
  float* out = (float*)d_out;

  char* ws = (char*)d_ws;
  size_t off = 0;
  auto alloc = [&](size_t bytes) { void* p = ws + off; off += (bytes + 255) & ~255ull; return p; };
  unsigned short* d1w_bf = (unsigned short*)alloc(16384 * 2);
  unsigned short* d2w_bf = (unsigned short*)alloc(49152 * 2);
  unsigned short* Wm     = (unsigned short*)alloc(655360 * 2);
  unsigned short* Wcb    = (unsigned short*)alloc(655360 * 2);
  float* bm              = (float*)alloc(2560 * 4);
  float* bc              = (float*)alloc(2560 * 4);
  unsigned short* obs_bf = (unsigned short*)alloc((size_t)NAg * BB * DD * 2);
  unsigned short* cat    = (unsigned short*)alloc((size_t)NAg * BB * CATW * 2);
  unsigned short* h0bf   = (unsigned short*)alloc((size_t)NAg * BB * DD * 2);

  float* out_h = out + (size_t)NAg * BB * AA;
  float* out_c = out_h + (size_t)NAg * BB * HH;

  k_prep<<<2048, 256, 0, stream>>>(d1w, d2w, mWih, mWhh, mbih, mbhh,
                                   cWih, cWhh, cbih, cbhh, h0,
                                   d1w_bf, d2w_bf, Wm, Wcb, bm, bc, h0bf);
  k_memobs<<<(NAg * BB) / 64, 512, 0, stream>>>(input, d1w_bf, d1b, h0bf, c0, Wm, bm,
                                                out_h, out_c, cat, obs_bf);
  k_comf<<<(NAg * BB) / 64, 512, 0, stream>>>(obs_bf, Wcb, bc, cat);
  k_d2<<<(NAg * BB) / 256, 256, 0, stream>>>(cat, d2w_bf, d2b, out);
}